// Round 14
// baseline (1317.495 us; speedup 1.0000x reference)
//
#include <hip/hip_runtime.h>

#define DEV __device__ __forceinline__

typedef __attribute__((ext_vector_type(8))) short short8;
typedef __attribute__((ext_vector_type(4))) short short4v;
typedef __attribute__((ext_vector_type(4))) float f32x4;
typedef __attribute__((ext_vector_type(8))) int int8v;
typedef __attribute__((ext_vector_type(4))) int int4v;

// ---------- bf16 helpers ----------
DEV float bf2f(unsigned short u) { return __uint_as_float(((unsigned int)u) << 16); }
DEV unsigned short f2bf(float f) {
    unsigned int u = __float_as_uint(f);
    u += 0x7FFFu + ((u >> 16) & 1u);   // RNE
    return (unsigned short)(u >> 16);
}

DEV float elu1(float v) { return v > 0.0f ? v + 1.0f : __expf(v); }

// pack 4 f32 -> 4 fp8(e4m3) bytes in one u32
DEV unsigned int pk4fp8(float a, float b, float c, float d) {
    int u = 0;
    u = __builtin_amdgcn_cvt_pk_fp8_f32(a, b, u, false);
    u = __builtin_amdgcn_cvt_pk_fp8_f32(c, d, u, true);
    return (unsigned int)u;
}

// ---------- async global->LDS, 16B per lane ----------
DEV void gload_lds16(const void* g, void* l) {
    __builtin_amdgcn_global_load_lds(
        (__attribute__((address_space(1))) unsigned int*)(g),
        (__attribute__((address_space(3))) unsigned int*)(l),
        16, 0, 0);
}

// Problem constants: B=4, NQ=NC=4096, D=1024, H=16, HD=64
#define NROW 16384
#define DDIM 1024

// Uniform MX scales (every byte identical -> lane-mapping-proof):
#define SCL_ONE  0x7F7F7F7F   // 2^0
#define SCL_W    0x79797979   // 2^-6 (weights pre-scaled x64 at quantization)

// =====================================================================
// LayerNorm (wave-per-row, fp8 out) + weight-convert.
// blocks 0..8191: LN rows (4/block). blocks >= 8192: weights.
//   mats 0..2 (q_w,k_w,v_w): fp8 = fp8(w*64), scale 2^-6 at MFMA.
//   mat 3 (o_w): bf16 (consumed by bf16 gemm_out256).
// =====================================================================
__global__ __launch_bounds__(256) void ln_kernel(
    const float* __restrict__ query, const float* __restrict__ context,
    const float* __restrict__ lnq_g, const float* __restrict__ lnq_b,
    const float* __restrict__ lnk_g, const float* __restrict__ lnk_b,
    unsigned char* __restrict__ qln8, unsigned char* __restrict__ cln8,
    const float* __restrict__ q_w, const float* __restrict__ k_w,
    const float* __restrict__ v_w, const float* __restrict__ o_w,
    unsigned char* __restrict__ w8, unsigned short* __restrict__ wo)
{
    const int tid = threadIdx.x;
    if (blockIdx.x >= 8192) {
        const int i = (blockIdx.x - 8192) * 256 + tid;
        const int mat = i >> 18;
        const int idx = (i & 262143) * 4;
        const float* src = mat == 0 ? q_w : mat == 1 ? k_w : mat == 2 ? v_w : o_w;
        f32x4 v = *(const f32x4*)(src + idx);
        if (mat < 3) {
            unsigned int u = pk4fp8(v[0] * 64.0f, v[1] * 64.0f,
                                    v[2] * 64.0f, v[3] * 64.0f);
            *(unsigned int*)(w8 + (size_t)mat * 1048576 + idx) = u;
        } else {
            short4v o;
#pragma unroll
            for (int j = 0; j < 4; ++j) o[j] = (short)f2bf(v[j]);
            *(short4v*)(wo + idx) = o;
        }
        return;
    }

    const int lane = tid & 63, w = tid >> 6;
    const int row = blockIdx.x * 4 + w;          // 0..32767
    const bool isq = row < NROW;
    const int r = isq ? row : row - NROW;
    const float* src = (isq ? query : context) + (size_t)r * DDIM;
    const float* g   = isq ? lnq_g : lnk_g;
    const float* bb  = isq ? lnq_b : lnk_b;
    unsigned char* dst = (isq ? qln8 : cln8) + (size_t)r * DDIM;

    f32x4 x[4];
    float s = 0.0f, sq = 0.0f;
#pragma unroll
    for (int j = 0; j < 4; ++j) {
        x[j] = *(const f32x4*)(src + j * 256 + lane * 4);
#pragma unroll
        for (int e = 0; e < 4; ++e) { s += x[j][e]; sq += x[j][e] * x[j][e]; }
    }
#pragma unroll
    for (int off = 32; off; off >>= 1) {
        s  += __shfl_xor(s, off);
        sq += __shfl_xor(sq, off);
    }
    const float mu  = s * (1.0f / DDIM);
    const float var = sq * (1.0f / DDIM) - mu * mu;
    const float rstd = rsqrtf(var + 1e-5f);

#pragma unroll
    for (int j = 0; j < 4; ++j) {
        f32x4 gv = *(const f32x4*)(g  + j * 256 + lane * 4);
        f32x4 bv = *(const f32x4*)(bb + j * 256 + lane * 4);
        f32x4 y;
#pragma unroll
        for (int e = 0; e < 4; ++e)
            y[e] = (x[j][e] - mu) * rstd * gv[e] + bv[e];
        *(unsigned int*)(dst + j * 256 + lane * 4) = pk4fp8(y[0], y[1], y[2], y[3]);
    }
}

// =====================================================================
// MX-fp8 projection GEMM: C = A @ B^T, K=1024, fp8 e4m3 operands,
// mfma_scale_f32_16x16x128_f8f6f4 (K=128/instr, 2x bf16 rate), uniform
// byte-broadcast scales. 512 thr / 8 waves (2Mx4N), wave tile 32x64,
// block 64x256, BK=128 (128 B/row -> identical staging/XOR-swizzle
// pattern to the verified bf16 BK=64 core). 40 KiB LDS, 2 blocks/CU.
//   l <  1024 : Qm  = elu1(QLN8 @ WQ8^T * 2^-6 + q_b)        (bf16 out)
//   l >= 1024 : KVT = f(WKV8 @ CLN8^T * 2^-6 + bias)         (bf16 out)
// =====================================================================
__global__ __launch_bounds__(512, 4) void gemm_qkv8(
    const unsigned char* __restrict__ QLN8, const unsigned char* __restrict__ CLN8,
    const unsigned char* __restrict__ W8,
    unsigned short* __restrict__ Qm, unsigned short* __restrict__ KVT,
    const float* __restrict__ q_b, const float* __restrict__ k_b,
    const float* __restrict__ v_b)
{
    __shared__ __attribute__((aligned(16))) unsigned char sA[64 * 128];
    __shared__ __attribute__((aligned(16))) unsigned char sB[256 * 128];

    const int bid = blockIdx.x;                  // 3072 blocks
    const int l = (bid & 7) * 384 + (bid >> 3);  // XCD-chunked

    const int tid = threadIdx.x;
    const int lane = tid & 63, w = tid >> 6;
    const int wr = w >> 2, wc = w & 3;           // 2 x 4 wave grid
    const int lr = lane & 15, lg = lane >> 4;

    const bool isQ = l < 1024;
    int m0, n0;
    const unsigned char *Ap, *Bp;
    int sclA, sclB;
    if (isQ) {
        m0 = (l >> 2) * 64; n0 = (l & 3) * 256;
        Ap = QLN8 + (size_t)m0 * 1024;           // activations, scale 1
        Bp = W8   + (size_t)n0 * 1024;           // WQ8, scale 2^-6
        sclA = SCL_ONE; sclB = SCL_W;
    } else {
        const int r = l - 1024;                  // 0..2047
        m0 = (r & 31) * 64; n0 = (r >> 5) * 256;
        Ap = W8 + 1048576 + (size_t)m0 * 1024;   // WK8;WV8 rows 0..2047
        Bp = CLN8 + (size_t)n0 * 1024;
        sclA = SCL_W; sclB = SCL_ONE;
    }

    // staging: thread t -> row t>>3 (+64j for B), 16B chunk (t&7),
    // global chunk XOR-swizzled so swizzled LDS reads return linear data.
    const int srow = tid >> 3;
    const int cswz = (tid & 7) ^ (srow & 7);
    const unsigned char* gA = Ap + (size_t)srow * 1024 + cswz * 16;
    const unsigned char* gB = Bp + (size_t)srow * 1024 + cswz * 16;
    unsigned char* dA = sA + tid * 16;
    unsigned char* dB = sB + tid * 16;

    f32x4 acc[2][4];
#pragma unroll
    for (int i = 0; i < 2; ++i)
#pragma unroll
        for (int j = 0; j < 4; ++j)
#pragma unroll
            for (int e = 0; e < 4; ++e) acc[i][j][e] = 0.0f;

#define STG(T)                                                                \
    {                                                                         \
        const int ko = (T) * 128;                                             \
        gload_lds16(gA + ko, dA);                                             \
        _Pragma("unroll")                                                     \
        for (int j = 0; j < 4; ++j)                                           \
            gload_lds16(gB + (size_t)j * 65536 + ko, dB + j * 8192);          \
    }

    STG(0);
    for (int t = 0; t < 8; ++t) {
        asm volatile("s_waitcnt vmcnt(0)" ::: "memory");
        __builtin_amdgcn_s_barrier();

        // frag = 32 contiguous k-bytes per lane at kbase = lg*32
        // -> linear chunks 2lg, 2lg+1, read via XOR swizzle (row&7 == lr&7)
        const int p = lr & 7;
        const int c0 = ((2 * lg) ^ p) * 16, c1 = ((2 * lg + 1) ^ p) * 16;
        int8v af[2], bf[4];
#pragma unroll
        for (int mt = 0; mt < 2; ++mt) {
            const int rb = (wr * 32 + mt * 16 + lr) * 128;
            int4v lo = *(const int4v*)(sA + rb + c0);
            int4v hi = *(const int4v*)(sA + rb + c1);
#pragma unroll
            for (int e = 0; e < 4; ++e) { af[mt][e] = lo[e]; af[mt][4 + e] = hi[e]; }
        }
#pragma unroll
        for (int nt = 0; nt < 4; ++nt) {
            const int rb = (wc * 64 + nt * 16 + lr) * 128;
            int4v lo = *(const int4v*)(sB + rb + c0);
            int4v hi = *(const int4v*)(sB + rb + c1);
#pragma unroll
            for (int e = 0; e < 4; ++e) { bf[nt][e] = lo[e]; bf[nt][4 + e] = hi[e]; }
        }
        asm volatile("s_waitcnt lgkmcnt(0)" ::: "memory");  // reads done
        __builtin_amdgcn_s_barrier();                       // all waves done
        if (t < 7) STG(t + 1);                              // overlaps MFMA

        __builtin_amdgcn_s_setprio(1);
#pragma unroll
        for (int mt = 0; mt < 2; ++mt)
#pragma unroll
            for (int nt = 0; nt < 4; ++nt)
                acc[mt][nt] = __builtin_amdgcn_mfma_scale_f32_16x16x128_f8f6f4(
                    af[mt], bf[nt], acc[mt][nt], 0, 0, 0, sclA, 0, sclB);
        __builtin_amdgcn_s_setprio(0);
    }
#undef STG

#pragma unroll
    for (int mt = 0; mt < 2; ++mt)
#pragma unroll
        for (int nt = 0; nt < 4; ++nt) {
            const int col = n0 + wc * 64 + nt * 16 + lr;
#pragma unroll
            for (int i = 0; i < 4; ++i) {
                const int row = m0 + wr * 32 + mt * 16 + lg * 4 + i;
                float v = acc[mt][nt][i];
                if (isQ) {
                    v = elu1(v + q_b[col]);
                    Qm[(size_t)row * 1024 + col] = f2bf(v);
                } else {
                    if (row < 1024) v = elu1(v + k_b[row]);
                    else            v = v + v_b[row - 1024];
                    KVT[(size_t)row * NROW + col] = f2bf(v);
                }
            }
        }
}

// =====================================================================
// O-projection: round-5 deep-pipelined 256x256/BK=64/8-wave bf16 kernel.
// =====================================================================
__global__ __launch_bounds__(512, 2) void gemm_out256(
    const unsigned short* __restrict__ A, const unsigned short* __restrict__ Bm,
    float* __restrict__ Cout, const float* __restrict__ bias,
    const float* __restrict__ resid)
{
    __shared__ __attribute__((aligned(16))) unsigned short smem[65536];
    unsigned short* sAb = smem;           // 2 x 16384
    unsigned short* sBb = smem + 32768;   // 2 x 16384

    const int bid = blockIdx.x;           // 256 blocks
    const int l = (bid & 7) * 32 + (bid >> 3);
    const int m0 = (l >> 2) * 256, n0 = (l & 3) * 256;

    const int tid = threadIdx.x;
    const int lane = tid & 63, w = tid >> 6;
    const int wr = w >> 2, wc = w & 3;          // 2 x 4 wave grid
    const int lr = lane & 15, lg = lane >> 4;

    const int srow = tid >> 3;
    const int cswz = (tid & 7) ^ (srow & 7);
    const unsigned short* gA0 = A  + (size_t)(m0 + srow) * 1024 + cswz * 8;
    const unsigned short* gB0 = Bm + (size_t)(n0 + srow) * 1024 + cswz * 8;

    const int sw0 = ((0 + lg) ^ (lr & 7)) * 8;
    const int sw1 = ((4 + lg) ^ (lr & 7)) * 8;

    f32x4 acc[8][4];
#pragma unroll
    for (int i = 0; i < 8; ++i)
#pragma unroll
        for (int j = 0; j < 4; ++j)
#pragma unroll
            for (int e = 0; e < 4; ++e) acc[i][j][e] = 0.0f;

#define STG(GP, SP, T)                                                        \
    {                                                                         \
        const unsigned short* g = (GP) + (T) * 64;                            \
        unsigned short* d = (SP) + ((T) & 1) * 16384 + tid * 8;               \
        _Pragma("unroll")                                                     \
        for (int L = 0; L < 4; ++L)                                           \
            gload_lds16(g + (size_t)L * 65536, d + L * 4096);                 \
    }

    STG(gB0, sBb, 0); STG(gA0, sAb, 0); STG(gB0, sBb, 1); STG(gA0, sAb, 1);
    asm volatile("s_waitcnt vmcnt(8)" ::: "memory");
    __builtin_amdgcn_s_barrier();

    short8 bvl[2][2];
#pragma unroll
    for (int nt = 0; nt < 2; ++nt) {
        const int rb = (wc * 64 + nt * 16 + lr) * 64;
        bvl[nt][0] = *(const short8*)&sBb[rb + sw0];
        bvl[nt][1] = *(const short8*)&sBb[rb + sw1];
    }

    for (int t = 0; t < 16; ++t) {
        const unsigned short* bA = sAb + (t & 1) * 16384;
        const unsigned short* bB = sBb + (t & 1) * 16384;
        const unsigned short* bBn = sBb + ((t + 1) & 1) * 16384;
        short8 afl[4][2], afh[4][2], bvh[2][2], bvln[2][2];

        // ---- P0 ----
#pragma unroll
        for (int mt = 0; mt < 4; ++mt) {
            const int ra = (wr * 128 + mt * 16 + lr) * 64;
            afl[mt][0] = *(const short8*)&bA[ra + sw0];
            afl[mt][1] = *(const short8*)&bA[ra + sw1];
        }
#pragma unroll
        for (int mt = 0; mt < 4; ++mt) {
            const int ra = (wr * 128 + (mt + 4) * 16 + lr) * 64;
            afh[mt][0] = *(const short8*)&bA[ra + sw0];
            afh[mt][1] = *(const short8*)&bA[ra + sw1];
        }
        asm volatile("s_waitcnt lgkmcnt(8)" ::: "memory");
        __builtin_amdgcn_s_setprio(1);
#pragma unroll
        for (int kk = 0; kk < 2; ++kk)
#pragma unroll
            for (int mt = 0; mt < 4; ++mt)
#pragma unroll
                for (int nt = 0; nt < 2; ++nt)
                    acc[mt][nt] = __builtin_amdgcn_mfma_f32_16x16x32_bf16(
                        afl[mt][kk], bvl[nt][kk], acc[mt][nt], 0, 0, 0);
        __builtin_amdgcn_s_setprio(0);
        __builtin_amdgcn_s_barrier();

        // ---- P1 ----
#pragma unroll
        for (int nt = 0; nt < 2; ++nt) {
            const int rb = (wc * 64 + (nt + 2) * 16 + lr) * 64;
            bvh[nt][0] = *(const short8*)&bB[rb + sw0];
            bvh[nt][1] = *(const short8*)&bB[rb + sw1];
        }
        asm volatile("s_waitcnt lgkmcnt(4)" ::: "memory");
        __builtin_amdgcn_s_setprio(1);
#pragma unroll
        for (int kk = 0; kk < 2; ++kk)
#pragma unroll
            for (int mt = 0; mt < 4; ++mt)
#pragma unroll
                for (int nt = 0; nt < 2; ++nt)
                    acc[mt + 4][nt] = __builtin_amdgcn_mfma_f32_16x16x32_bf16(
                        afh[mt][kk], bvl[nt][kk], acc[mt + 4][nt], 0, 0, 0);
        __builtin_amdgcn_s_setprio(0);
        asm volatile("s_waitcnt vmcnt(0)" ::: "memory");
        __builtin_amdgcn_s_barrier();

        // ---- P2 ----
        if (t < 15) {
#pragma unroll
            for (int nt = 0; nt < 2; ++nt) {
                const int rb = (wc * 64 + nt * 16 + lr) * 64;
                bvln[nt][0] = *(const short8*)&bBn[rb + sw0];
                bvln[nt][1] = *(const short8*)&bBn[rb + sw1];
            }
        }
        if (t + 2 < 16) STG(gA0, sAb, t + 2);
        if (t < 15) asm volatile("s_waitcnt lgkmcnt(4)" ::: "memory");
        else        asm volatile("s_waitcnt lgkmcnt(0)" ::: "memory");
        __builtin_amdgcn_s_setprio(1);
#pragma unroll
        for (int kk = 0; kk < 2; ++kk)
#pragma unroll
            for (int mt = 0; mt < 4; ++mt)
#pragma unroll
                for (int nt = 0; nt < 2; ++nt)
                    acc[mt + 4][nt + 2] = __builtin_amdgcn_mfma_f32_16x16x32_bf16(
                        afh[mt][kk], bvh[nt][kk], acc[mt + 4][nt + 2], 0, 0, 0);
        __builtin_amdgcn_s_setprio(0);
        __builtin_amdgcn_s_barrier();

        // ---- P3 ----
        if (t + 2 < 16) STG(gB0, sBb, t + 2);
        __builtin_amdgcn_s_setprio(1);
#pragma unroll
        for (int kk = 0; kk < 2; ++kk)
#pragma unroll
            for (int mt = 0; mt < 4; ++mt)
#pragma unroll
                for (int nt = 0; nt < 2; ++nt)
                    acc[mt][nt + 2] = __builtin_amdgcn_mfma_f32_16x16x32_bf16(
                        afl[mt][kk], bvh[nt][kk], acc[mt][nt + 2], 0, 0, 0);
        __builtin_amdgcn_s_setprio(0);

        if (t < 15) {
#pragma unroll
            for (int nt = 0; nt < 2; ++nt) {
                bvl[nt][0] = bvln[nt][0];
                bvl[nt][1] = bvln[nt][1];
            }
        }
    }
#undef STG

#pragma unroll
    for (int mt = 0; mt < 8; ++mt) {
#pragma unroll
        for (int nt = 0; nt < 4; ++nt) {
            const int col = n0 + wc * 64 + nt * 16 + lr;
#pragma unroll
            for (int i = 0; i < 4; ++i) {
                const int row = m0 + wr * 128 + mt * 16 + lg * 4 + i;
                Cout[(size_t)row * 1024 + col] =
                    acc[mt][nt][i] + bias[col] + resid[(size_t)row * 1024 + col];
            }
        }
    }
}

// =====================================================================
// KV partials + Ksum partials; quadrant-per-wave, 16 n-splits.
// =====================================================================
__global__ __launch_bounds__(256) void kv_kernel(
    const unsigned short* __restrict__ VT, const unsigned short* __restrict__ KT,
    float* __restrict__ KVTp, float* __restrict__ Ksump)
{
    const int bh = blockIdx.x, sp = blockIdx.y;   // 64 x 16
    const int b = bh >> 4, h = bh & 15;
    const int tid = threadIdx.x, lane = tid & 63, w = tid >> 6;
    const int lr = lane & 15, lg = lane >> 4;
    const int eh = (w >> 1) * 32, dh = (w & 1) * 32;

    f32x4 acc[2][2];
#pragma unroll
    for (int i = 0; i < 2; ++i)
#pragma unroll
        for (int j = 0; j < 2; ++j)
#pragma unroll
            for (int e = 0; e < 4; ++e) acc[i][j][e] = 0.0f;
    float kp[2] = {0.0f, 0.0f};

    const size_t colbase = (size_t)b * 4096 + sp * 256 + lg * 8;
    const unsigned short* va = VT + (size_t)(h * 64 + eh + lr) * NROW + colbase;
    const unsigned short* ka = KT + (size_t)(h * 64 + dh + lr) * NROW + colbase;

    for (int ks = 0; ks < 8; ++ks) {
        short8 af[2], bfv[2];
        af[0]  = *(const short8*)(va + ks * 32);
        af[1]  = *(const short8*)(va + (size_t)16 * NROW + ks * 32);
        bfv[0] = *(const short8*)(ka + ks * 32);
        bfv[1] = *(const short8*)(ka + (size_t)16 * NROW + ks * 32);
#pragma unroll
        for (int mt = 0; mt < 2; ++mt)
#pragma unroll
            for (int nt = 0; nt < 2; ++nt)
                acc[mt][nt] = __builtin_amdgcn_mfma_f32_16x16x32_bf16(
                    af[mt], bfv[nt], acc[mt][nt], 0, 0, 0);
        if (w < 2) {
#pragma unroll
            for (int nt = 0; nt < 2; ++nt)
#pragma unroll
                for (int j = 0; j < 8; ++j)
                    kp[nt] += bf2f((unsigned short)bfv[nt][j]);
        }
    }

    float* out = KVTp + ((size_t)sp * 64 + bh) * 4096;
#pragma unroll
    for (int mt = 0; mt < 2; ++mt)
#pragma unroll
        for (int nt = 0; nt < 2; ++nt)
#pragma unroll
            for (int i = 0; i < 4; ++i)
                out[(eh + mt * 16 + lg * 4 + i) * 64 + dh + nt * 16 + lr] =
                    acc[mt][nt][i];

    if (w < 2) {
#pragma unroll
        for (int nt = 0; nt < 2; ++nt) {
            kp[nt] += __shfl_xor(kp[nt], 16);
            kp[nt] += __shfl_xor(kp[nt], 32);
        }
        if (lane < 16) {
#pragma unroll
            for (int nt = 0; nt < 2; ++nt)
                Ksump[((size_t)sp * 64 + bh) * 64 + dh + nt * 16 + lane] = kp[nt];
        }
    }
}

// =====================================================================
// Reduce the 16 split-partials once: KVs[bh][4096], Ks[bh][64].
// =====================================================================
__global__ __launch_bounds__(256) void kvred_kernel(
    const float* __restrict__ KVTp, const float* __restrict__ Ksump,
    float* __restrict__ KVs, float* __restrict__ Ks)
{
    const int bh = blockIdx.x;
    const int tid = threadIdx.x;
    for (int i = tid * 4; i < 4096; i += 1024) {
        f32x4 s = {0.0f, 0.0f, 0.0f, 0.0f};
#pragma unroll
        for (int sp = 0; sp < 16; ++sp) {
            f32x4 v = *(const f32x4*)(KVTp + ((size_t)sp * 64 + bh) * 4096 + i);
            s[0] += v[0]; s[1] += v[1]; s[2] += v[2]; s[3] += v[3];
        }
        *(f32x4*)(KVs + (size_t)bh * 4096 + i) = s;
    }
    if (tid < 64) {
        float s = 0.0f;
#pragma unroll
        for (int sp = 0; sp < 16; ++sp)
            s += Ksump[((size_t)sp * 64 + bh) * 64 + tid];
        Ks[bh * 64 + tid] = s;
    }
}

// =====================================================================
// A2[n][h*64+e] = (sum_d Q[n][h*64+d] * KV[d][e]) * invZ(n,h); z fused.
// =====================================================================
__global__ __launch_bounds__(256) void a2_kernel(
    const unsigned short* __restrict__ Q, const float* __restrict__ KVs,
    const float* __restrict__ Ks, unsigned short* __restrict__ A2)
{
    const int m0 = blockIdx.x * 128, h = blockIdx.y;
    const int b = m0 >> 12, bh = (b << 4) + h;
    const int tid = threadIdx.x, lane = tid & 63, w = tid >> 6;
    const int wr = w >> 1, wc = w & 1;
    const int lr = lane & 15, lg = lane >> 4;

    __shared__ float ksum_s[64];
    if (tid < 64) ksum_s[tid] = Ks[bh * 64 + tid];
    __syncthreads();

    f32x4 acc[4][2];
#pragma unroll
    for (int i = 0; i < 4; ++i)
#pragma unroll
        for (int j = 0; j < 2; ++j)
#pragma unroll
            for (int e = 0; e < 4; ++e) acc[i][j][e] = 0.0f;
    float zp[4] = {0.0f, 0.0f, 0.0f, 0.0f};

    const unsigned short* qa = Q + (size_t)(m0 + wr * 64 + lr) * DDIM + h * 64 + lg * 8;
    const float* kvb = KVs + (size_t)bh * 4096 + (wc * 32 + lr) * 64 + lg * 8;

#pragma unroll
    for (int ks = 0; ks < 2; ++ks) {
        short8 af[4];
#pragma unroll
        for (int mt = 0; mt < 4; ++mt)
            af[mt] = *(const short8*)(qa + (size_t)mt * 16 * DDIM + ks * 32);
#pragma unroll
        for (int mt = 0; mt < 4; ++mt)
#pragma unroll
            for (int j = 0; j < 8; ++j)
                zp[mt] += bf2f((unsigned short)af[mt][j]) * ksum_s[ks * 32 + lg * 8 + j];
        short8 bfv[2];
#pragma unroll
        for (int nt = 0; nt < 2; ++nt) {
            const float* p = kvb + nt * 16 * 64 + ks * 32;
            f32x4 v0 = *(const f32x4*)(p);
            f32x4 v1 = *(const f32x4*)(p + 4);
            short8 t;
#pragma unroll
            for (int j = 0; j < 4; ++j) {
                t[j]     = (short)f2bf(v0[j]);
                t[j + 4] = (short)f2bf(v1[j]);
            }
            bfv[nt] = t;
        }
#pragma unroll
        for (int mt = 0; mt < 4; ++mt)
#pragma unroll
            for (int nt = 0; nt < 2; ++nt)
                acc[mt][nt] = __builtin_amdgcn_mfma_f32_16x16x32_bf16(
                    af[mt], bfv[nt], acc[mt][nt], 0, 0, 0);
    }

    float zinv[4];
#pragma unroll
    for (int mt = 0; mt < 4; ++mt) {
        zp[mt] += __shfl_xor(zp[mt], 16);
        zp[mt] += __shfl_xor(zp[mt], 32);
        zinv[mt] = 1.0f / fmaxf(zp[mt], 1e-6f);
    }

#pragma unroll
    for (int mt = 0; mt < 4; ++mt)
#pragma unroll
        for (int nt = 0; nt < 2; ++nt)
#pragma unroll
            for (int i = 0; i < 4; ++i) {
                const int row = m0 + wr * 64 + mt * 16 + lg * 4 + i;
                const int col = h * 64 + wc * 32 + nt * 16 + lr;
                const float zi = __shfl(zinv[mt], lg * 4 + i);
                const float v = acc[mt][nt][i] * zi;
                A2[(size_t)row * DDIM + col] = f2bf(v);
            }
}

// =====================================================================
// host
// =====================================================================
extern "C" void kernel_launch(void* const* d_in, const int* in_sizes, int n_in,
                              void* d_out, int out_size, void* d_ws, size_t ws_size,
                              hipStream_t stream)
{
    const float* query   = (const float*)d_in[0];
    const float* context = (const float*)d_in[1];
    const float* q_w = (const float*)d_in[2];
    const float* q_b = (const float*)d_in[3];
    const float* k_w = (const float*)d_in[4];
    const float* k_b = (const float*)d_in[5];
    const float* v_w = (const float*)d_in[6];
    const float* v_b = (const float*)d_in[7];
    const float* o_w = (const float*)d_in[8];
    const float* o_b = (const float*)d_in[9];
    const float* lnq_g = (const float*)d_in[10];
    const float* lnq_b = (const float*)d_in[11];
    const float* lnk_g = (const float*)d_in[12];
    const float* lnk_b = (const float*)d_in[13];

    char* ws = (char*)d_ws;
    unsigned char* W8   = (unsigned char*)(ws);                     // 0..3 MiB (WQ8,WK8,WV8 fp8 x64)
    unsigned short* WO  = (unsigned short*)(ws + (4u << 20));       // 4..6 bf16
    unsigned char* QLN8 = (unsigned char*)(ws + (8u << 20));        // 8..24 fp8
    unsigned char* CLN8 = (unsigned char*)(ws + (24u << 20));       // 24..40 fp8
    float* KVTp  = (float*)(ws + (40u << 20));                      // 40..56 (16 splits)
    float* Ksump = (float*)(ws + (56u << 20));                      // 256 KiB
    float* KVs   = (float*)(ws + (57u << 20));                      // 1 MiB
    float* Ks    = (float*)(ws + (58u << 20));                      // 16 KiB
    unsigned short* Qm  = (unsigned short*)(ws + (72u << 20));      // 72..104 bf16
    unsigned short* KT  = (unsigned short*)(ws + (104u << 20));     // KVT rows 0-1023
    unsigned short* VT  = (unsigned short*)(ws + (136u << 20));     // KVT rows 1024-2047
    unsigned short* A2  = (unsigned short*)(ws + (8u << 20));       // alias QLN8/CLN8 (dead after qkv)

    ln_kernel<<<8192 + 4096, 256, 0, stream>>>(
        query, context, lnq_g, lnq_b, lnk_g, lnk_b, QLN8, CLN8,
        q_w, k_w, v_w, o_w, W8, WO);
    gemm_qkv8<<<3072, 512, 0, stream>>>(QLN8, CLN8, W8, Qm, KT,
                                        q_b, k_b, v_b);
    kv_kernel<<<dim3(64, 16), 256, 0, stream>>>(VT, KT, KVTp, Ksump);
    kvred_kernel<<<64, 256, 0, stream>>>(KVTp, Ksump, KVs, Ks);
    a2_kernel<<<dim3(128, 16), 256, 0, stream>>>(Qm, KVs, Ks, A2);
    gemm_out256<<<256, 512, 0, stream>>>(A2, WO, (float*)d_out, o_b, query);
}

// Round 15
// 761.079 us; speedup vs baseline: 1.7311x; 1.7311x over previous
//
#include <hip/hip_runtime.h>

#define DEV __device__ __forceinline__

typedef __attribute__((ext_vector_type(8))) short short8;
typedef __attribute__((ext_vector_type(4))) short short4v;
typedef __attribute__((ext_vector_type(4))) float f32x4;
typedef __attribute__((ext_vector_type(8))) int int8v;
typedef __attribute__((ext_vector_type(4))) int int4v;

// ---------- bf16 helpers ----------
DEV float bf2f(unsigned short u) { return __uint_as_float(((unsigned int)u) << 16); }
DEV unsigned short f2bf(float f) {
    unsigned int u = __float_as_uint(f);
    u += 0x7FFFu + ((u >> 16) & 1u);   // RNE
    return (unsigned short)(u >> 16);
}

DEV float elu1(float v) { return v > 0.0f ? v + 1.0f : __expf(v); }

// pack 4 f32 -> 4 fp8(e4m3) bytes in one u32
DEV unsigned int pk4fp8(float a, float b, float c, float d) {
    int u = 0;
    u = __builtin_amdgcn_cvt_pk_fp8_f32(a, b, u, false);
    u = __builtin_amdgcn_cvt_pk_fp8_f32(c, d, u, true);
    return (unsigned int)u;
}

// ---------- async global->LDS, 16B per lane ----------
DEV void gload_lds16(const void* g, void* l) {
    __builtin_amdgcn_global_load_lds(
        (__attribute__((address_space(1))) unsigned int*)(g),
        (__attribute__((address_space(3))) unsigned int*)(l),
        16, 0, 0);
}

// Problem constants: B=4, NQ=NC=4096, D=1024, H=16, HD=64
#define NROW 16384
#define DDIM 1024

// Uniform MX scales (every byte identical -> lane-mapping-proof):
#define SCL_ONE  0x7F7F7F7F   // 2^0
#define SCL_W    0x79797979   // 2^-6 (weights pre-scaled x64 at quantization)

// =====================================================================
// LayerNorm (wave-per-row, fp8 out) + weight-convert.
// =====================================================================
__global__ __launch_bounds__(256) void ln_kernel(
    const float* __restrict__ query, const float* __restrict__ context,
    const float* __restrict__ lnq_g, const float* __restrict__ lnq_b,
    const float* __restrict__ lnk_g, const float* __restrict__ lnk_b,
    unsigned char* __restrict__ qln8, unsigned char* __restrict__ cln8,
    const float* __restrict__ q_w, const float* __restrict__ k_w,
    const float* __restrict__ v_w, const float* __restrict__ o_w,
    unsigned char* __restrict__ w8, unsigned short* __restrict__ wo)
{
    const int tid = threadIdx.x;
    if (blockIdx.x >= 8192) {
        const int i = (blockIdx.x - 8192) * 256 + tid;
        const int mat = i >> 18;
        const int idx = (i & 262143) * 4;
        const float* src = mat == 0 ? q_w : mat == 1 ? k_w : mat == 2 ? v_w : o_w;
        f32x4 v = *(const f32x4*)(src + idx);
        if (mat < 3) {
            unsigned int u = pk4fp8(v[0] * 64.0f, v[1] * 64.0f,
                                    v[2] * 64.0f, v[3] * 64.0f);
            *(unsigned int*)(w8 + (size_t)mat * 1048576 + idx) = u;
        } else {
            short4v o;
#pragma unroll
            for (int j = 0; j < 4; ++j) o[j] = (short)f2bf(v[j]);
            *(short4v*)(wo + idx) = o;
        }
        return;
    }

    const int lane = tid & 63, w = tid >> 6;
    const int row = blockIdx.x * 4 + w;          // 0..32767
    const bool isq = row < NROW;
    const int r = isq ? row : row - NROW;
    const float* src = (isq ? query : context) + (size_t)r * DDIM;
    const float* g   = isq ? lnq_g : lnk_g;
    const float* bb  = isq ? lnq_b : lnk_b;
    unsigned char* dst = (isq ? qln8 : cln8) + (size_t)r * DDIM;

    f32x4 x[4];
    float s = 0.0f, sq = 0.0f;
#pragma unroll
    for (int j = 0; j < 4; ++j) {
        x[j] = *(const f32x4*)(src + j * 256 + lane * 4);
#pragma unroll
        for (int e = 0; e < 4; ++e) { s += x[j][e]; sq += x[j][e] * x[j][e]; }
    }
#pragma unroll
    for (int off = 32; off; off >>= 1) {
        s  += __shfl_xor(s, off);
        sq += __shfl_xor(sq, off);
    }
    const float mu  = s * (1.0f / DDIM);
    const float var = sq * (1.0f / DDIM) - mu * mu;
    const float rstd = rsqrtf(var + 1e-5f);

#pragma unroll
    for (int j = 0; j < 4; ++j) {
        f32x4 gv = *(const f32x4*)(g  + j * 256 + lane * 4);
        f32x4 bv = *(const f32x4*)(bb + j * 256 + lane * 4);
        f32x4 y;
#pragma unroll
        for (int e = 0; e < 4; ++e)
            y[e] = (x[j][e] - mu) * rstd * gv[e] + bv[e];
        *(unsigned int*)(dst + j * 256 + lane * 4) = pk4fp8(y[0], y[1], y[2], y[3]);
    }
}

// =====================================================================
// MX-fp8 projection GEMM (round-14 structure, launch bounds relaxed to
// (512,2): the (512,4) 128-reg cap spilled the fragment set -> 2 GB of
// scratch writes -> 1218 us. ~130 live regs fit in 256 with headroom.)
// =====================================================================
__global__ __launch_bounds__(512, 2) void gemm_qkv8(
    const unsigned char* __restrict__ QLN8, const unsigned char* __restrict__ CLN8,
    const unsigned char* __restrict__ W8,
    unsigned short* __restrict__ Qm, unsigned short* __restrict__ KVT,
    const float* __restrict__ q_b, const float* __restrict__ k_b,
    const float* __restrict__ v_b)
{
    __shared__ __attribute__((aligned(16))) unsigned char sA[64 * 128];
    __shared__ __attribute__((aligned(16))) unsigned char sB[256 * 128];

    const int bid = blockIdx.x;                  // 3072 blocks
    const int l = (bid & 7) * 384 + (bid >> 3);  // XCD-chunked

    const int tid = threadIdx.x;
    const int lane = tid & 63, w = tid >> 6;
    const int wr = w >> 2, wc = w & 3;           // 2 x 4 wave grid
    const int lr = lane & 15, lg = lane >> 4;

    const bool isQ = l < 1024;
    int m0, n0;
    const unsigned char *Ap, *Bp;
    int sclA, sclB;
    if (isQ) {
        m0 = (l >> 2) * 64; n0 = (l & 3) * 256;
        Ap = QLN8 + (size_t)m0 * 1024;           // activations, scale 1
        Bp = W8   + (size_t)n0 * 1024;           // WQ8, scale 2^-6
        sclA = SCL_ONE; sclB = SCL_W;
    } else {
        const int r = l - 1024;                  // 0..2047
        m0 = (r & 31) * 64; n0 = (r >> 5) * 256;
        Ap = W8 + 1048576 + (size_t)m0 * 1024;   // WK8;WV8 rows 0..2047
        Bp = CLN8 + (size_t)n0 * 1024;
        sclA = SCL_W; sclB = SCL_ONE;
    }

    const int srow = tid >> 3;
    const int cswz = (tid & 7) ^ (srow & 7);
    const unsigned char* gA = Ap + (size_t)srow * 1024 + cswz * 16;
    const unsigned char* gB = Bp + (size_t)srow * 1024 + cswz * 16;
    unsigned char* dA = sA + tid * 16;
    unsigned char* dB = sB + tid * 16;

    f32x4 acc[2][4];
#pragma unroll
    for (int i = 0; i < 2; ++i)
#pragma unroll
        for (int j = 0; j < 4; ++j)
#pragma unroll
            for (int e = 0; e < 4; ++e) acc[i][j][e] = 0.0f;

#define STG(T)                                                                \
    {                                                                         \
        const int ko = (T) * 128;                                             \
        gload_lds16(gA + ko, dA);                                             \
        _Pragma("unroll")                                                     \
        for (int j = 0; j < 4; ++j)                                           \
            gload_lds16(gB + (size_t)j * 65536 + ko, dB + j * 8192);          \
    }

    STG(0);
    for (int t = 0; t < 8; ++t) {
        asm volatile("s_waitcnt vmcnt(0)" ::: "memory");
        __builtin_amdgcn_s_barrier();

        // frag = 32 contiguous k-bytes per lane at kbase = lg*32
        const int p = lr & 7;
        const int c0 = ((2 * lg) ^ p) * 16, c1 = ((2 * lg + 1) ^ p) * 16;
        int8v af[2], bf[4];
#pragma unroll
        for (int mt = 0; mt < 2; ++mt) {
            const int rb = (wr * 32 + mt * 16 + lr) * 128;
            int4v lo = *(const int4v*)(sA + rb + c0);
            int4v hi = *(const int4v*)(sA + rb + c1);
#pragma unroll
            for (int e = 0; e < 4; ++e) { af[mt][e] = lo[e]; af[mt][4 + e] = hi[e]; }
        }
#pragma unroll
        for (int nt = 0; nt < 4; ++nt) {
            const int rb = (wc * 64 + nt * 16 + lr) * 128;
            int4v lo = *(const int4v*)(sB + rb + c0);
            int4v hi = *(const int4v*)(sB + rb + c1);
#pragma unroll
            for (int e = 0; e < 4; ++e) { bf[nt][e] = lo[e]; bf[nt][4 + e] = hi[e]; }
        }
        asm volatile("s_waitcnt lgkmcnt(0)" ::: "memory");  // reads done
        __builtin_amdgcn_s_barrier();                       // all waves done
        if (t < 7) STG(t + 1);                              // overlaps MFMA

        __builtin_amdgcn_s_setprio(1);
#pragma unroll
        for (int mt = 0; mt < 2; ++mt)
#pragma unroll
            for (int nt = 0; nt < 4; ++nt)
                acc[mt][nt] = __builtin_amdgcn_mfma_scale_f32_16x16x128_f8f6f4(
                    af[mt], bf[nt], acc[mt][nt], 0, 0, 0, sclA, 0, sclB);
        __builtin_amdgcn_s_setprio(0);
    }
#undef STG

#pragma unroll
    for (int mt = 0; mt < 2; ++mt)
#pragma unroll
        for (int nt = 0; nt < 4; ++nt) {
            const int col = n0 + wc * 64 + nt * 16 + lr;
#pragma unroll
            for (int i = 0; i < 4; ++i) {
                const int row = m0 + wr * 32 + mt * 16 + lg * 4 + i;
                float v = acc[mt][nt][i];
                if (isQ) {
                    v = elu1(v + q_b[col]);
                    Qm[(size_t)row * 1024 + col] = f2bf(v);
                } else {
                    if (row < 1024) v = elu1(v + k_b[row]);
                    else            v = v + v_b[row - 1024];
                    KVT[(size_t)row * NROW + col] = f2bf(v);
                }
            }
        }
}

// =====================================================================
// O-projection: round-5 deep-pipelined 256x256/BK=64/8-wave bf16 kernel.
// =====================================================================
__global__ __launch_bounds__(512, 2) void gemm_out256(
    const unsigned short* __restrict__ A, const unsigned short* __restrict__ Bm,
    float* __restrict__ Cout, const float* __restrict__ bias,
    const float* __restrict__ resid)
{
    __shared__ __attribute__((aligned(16))) unsigned short smem[65536];
    unsigned short* sAb = smem;           // 2 x 16384
    unsigned short* sBb = smem + 32768;   // 2 x 16384

    const int bid = blockIdx.x;           // 256 blocks
    const int l = (bid & 7) * 32 + (bid >> 3);
    const int m0 = (l >> 2) * 256, n0 = (l & 3) * 256;

    const int tid = threadIdx.x;
    const int lane = tid & 63, w = tid >> 6;
    const int wr = w >> 2, wc = w & 3;          // 2 x 4 wave grid
    const int lr = lane & 15, lg = lane >> 4;

    const int srow = tid >> 3;
    const int cswz = (tid & 7) ^ (srow & 7);
    const unsigned short* gA0 = A  + (size_t)(m0 + srow) * 1024 + cswz * 8;
    const unsigned short* gB0 = Bm + (size_t)(n0 + srow) * 1024 + cswz * 8;

    const int sw0 = ((0 + lg) ^ (lr & 7)) * 8;
    const int sw1 = ((4 + lg) ^ (lr & 7)) * 8;

    f32x4 acc[8][4];
#pragma unroll
    for (int i = 0; i < 8; ++i)
#pragma unroll
        for (int j = 0; j < 4; ++j)
#pragma unroll
            for (int e = 0; e < 4; ++e) acc[i][j][e] = 0.0f;

#define STG(GP, SP, T)                                                        \
    {                                                                         \
        const unsigned short* g = (GP) + (T) * 64;                            \
        unsigned short* d = (SP) + ((T) & 1) * 16384 + tid * 8;               \
        _Pragma("unroll")                                                     \
        for (int L = 0; L < 4; ++L)                                           \
            gload_lds16(g + (size_t)L * 65536, d + L * 4096);                 \
    }

    STG(gB0, sBb, 0); STG(gA0, sAb, 0); STG(gB0, sBb, 1); STG(gA0, sAb, 1);
    asm volatile("s_waitcnt vmcnt(8)" ::: "memory");
    __builtin_amdgcn_s_barrier();

    short8 bvl[2][2];
#pragma unroll
    for (int nt = 0; nt < 2; ++nt) {
        const int rb = (wc * 64 + nt * 16 + lr) * 64;
        bvl[nt][0] = *(const short8*)&sBb[rb + sw0];
        bvl[nt][1] = *(const short8*)&sBb[rb + sw1];
    }

    for (int t = 0; t < 16; ++t) {
        const unsigned short* bA = sAb + (t & 1) * 16384;
        const unsigned short* bB = sBb + (t & 1) * 16384;
        const unsigned short* bBn = sBb + ((t + 1) & 1) * 16384;
        short8 afl[4][2], afh[4][2], bvh[2][2], bvln[2][2];

        // ---- P0 ----
#pragma unroll
        for (int mt = 0; mt < 4; ++mt) {
            const int ra = (wr * 128 + mt * 16 + lr) * 64;
            afl[mt][0] = *(const short8*)&bA[ra + sw0];
            afl[mt][1] = *(const short8*)&bA[ra + sw1];
        }
#pragma unroll
        for (int mt = 0; mt < 4; ++mt) {
            const int ra = (wr * 128 + (mt + 4) * 16 + lr) * 64;
            afh[mt][0] = *(const short8*)&bA[ra + sw0];
            afh[mt][1] = *(const short8*)&bA[ra + sw1];
        }
        asm volatile("s_waitcnt lgkmcnt(8)" ::: "memory");
        __builtin_amdgcn_s_setprio(1);
#pragma unroll
        for (int kk = 0; kk < 2; ++kk)
#pragma unroll
            for (int mt = 0; mt < 4; ++mt)
#pragma unroll
                for (int nt = 0; nt < 2; ++nt)
                    acc[mt][nt] = __builtin_amdgcn_mfma_f32_16x16x32_bf16(
                        afl[mt][kk], bvl[nt][kk], acc[mt][nt], 0, 0, 0);
        __builtin_amdgcn_s_setprio(0);
        __builtin_amdgcn_s_barrier();

        // ---- P1 ----
#pragma unroll
        for (int nt = 0; nt < 2; ++nt) {
            const int rb = (wc * 64 + (nt + 2) * 16 + lr) * 64;
            bvh[nt][0] = *(const short8*)&bB[rb + sw0];
            bvh[nt][1] = *(const short8*)&bB[rb + sw1];
        }
        asm volatile("s_waitcnt lgkmcnt(4)" ::: "memory");
        __builtin_amdgcn_s_setprio(1);
#pragma unroll
        for (int kk = 0; kk < 2; ++kk)
#pragma unroll
            for (int mt = 0; mt < 4; ++mt)
#pragma unroll
                for (int nt = 0; nt < 2; ++nt)
                    acc[mt + 4][nt] = __builtin_amdgcn_mfma_f32_16x16x32_bf16(
                        afh[mt][kk], bvl[nt][kk], acc[mt + 4][nt], 0, 0, 0);
        __builtin_amdgcn_s_setprio(0);
        asm volatile("s_waitcnt vmcnt(0)" ::: "memory");
        __builtin_amdgcn_s_barrier();

        // ---- P2 ----
        if (t < 15) {
#pragma unroll
            for (int nt = 0; nt < 2; ++nt) {
                const int rb = (wc * 64 + nt * 16 + lr) * 64;
                bvln[nt][0] = *(const short8*)&bBn[rb + sw0];
                bvln[nt][1] = *(const short8*)&bBn[rb + sw1];
            }
        }
        if (t + 2 < 16) STG(gA0, sAb, t + 2);
        if (t < 15) asm volatile("s_waitcnt lgkmcnt(4)" ::: "memory");
        else        asm volatile("s_waitcnt lgkmcnt(0)" ::: "memory");
        __builtin_amdgcn_s_setprio(1);
#pragma unroll
        for (int kk = 0; kk < 2; ++kk)
#pragma unroll
            for (int mt = 0; mt < 4; ++mt)
#pragma unroll
                for (int nt = 0; nt < 2; ++nt)
                    acc[mt + 4][nt + 2] = __builtin_amdgcn_mfma_f32_16x16x32_bf16(
                        afh[mt][kk], bvh[nt][kk], acc[mt + 4][nt + 2], 0, 0, 0);
        __builtin_amdgcn_s_setprio(0);
        __builtin_amdgcn_s_barrier();

        // ---- P3 ----
        if (t + 2 < 16) STG(gB0, sBb, t + 2);
        __builtin_amdgcn_s_setprio(1);
#pragma unroll
        for (int kk = 0; kk < 2; ++kk)
#pragma unroll
            for (int mt = 0; mt < 4; ++mt)
#pragma unroll
                for (int nt = 0; nt < 2; ++nt)
                    acc[mt][nt + 2] = __builtin_amdgcn_mfma_f32_16x16x32_bf16(
                        afl[mt][kk], bvh[nt][kk], acc[mt][nt + 2], 0, 0, 0);
        __builtin_amdgcn_s_setprio(0);

        if (t < 15) {
#pragma unroll
            for (int nt = 0; nt < 2; ++nt) {
                bvl[nt][0] = bvln[nt][0];
                bvl[nt][1] = bvln[nt][1];
            }
        }
    }
#undef STG

#pragma unroll
    for (int mt = 0; mt < 8; ++mt) {
#pragma unroll
        for (int nt = 0; nt < 4; ++nt) {
            const int col = n0 + wc * 64 + nt * 16 + lr;
#pragma unroll
            for (int i = 0; i < 4; ++i) {
                const int row = m0 + wr * 128 + mt * 16 + lg * 4 + i;
                Cout[(size_t)row * 1024 + col] =
                    acc[mt][nt][i] + bias[col] + resid[(size_t)row * 1024 + col];
            }
        }
    }
}

// =====================================================================
// KV partials + Ksum partials; quadrant-per-wave, 16 n-splits.
// =====================================================================
__global__ __launch_bounds__(256) void kv_kernel(
    const unsigned short* __restrict__ VT, const unsigned short* __restrict__ KT,
    float* __restrict__ KVTp, float* __restrict__ Ksump)
{
    const int bh = blockIdx.x, sp = blockIdx.y;   // 64 x 16
    const int b = bh >> 4, h = bh & 15;
    const int tid = threadIdx.x, lane = tid & 63, w = tid >> 6;
    const int lr = lane & 15, lg = lane >> 4;
    const int eh = (w >> 1) * 32, dh = (w & 1) * 32;

    f32x4 acc[2][2];
#pragma unroll
    for (int i = 0; i < 2; ++i)
#pragma unroll
        for (int j = 0; j < 2; ++j)
#pragma unroll
            for (int e = 0; e < 4; ++e) acc[i][j][e] = 0.0f;
    float kp[2] = {0.0f, 0.0f};

    const size_t colbase = (size_t)b * 4096 + sp * 256 + lg * 8;
    const unsigned short* va = VT + (size_t)(h * 64 + eh + lr) * NROW + colbase;
    const unsigned short* ka = KT + (size_t)(h * 64 + dh + lr) * NROW + colbase;

    for (int ks = 0; ks < 8; ++ks) {
        short8 af[2], bfv[2];
        af[0]  = *(const short8*)(va + ks * 32);
        af[1]  = *(const short8*)(va + (size_t)16 * NROW + ks * 32);
        bfv[0] = *(const short8*)(ka + ks * 32);
        bfv[1] = *(const short8*)(ka + (size_t)16 * NROW + ks * 32);
#pragma unroll
        for (int mt = 0; mt < 2; ++mt)
#pragma unroll
            for (int nt = 0; nt < 2; ++nt)
                acc[mt][nt] = __builtin_amdgcn_mfma_f32_16x16x32_bf16(
                    af[mt], bfv[nt], acc[mt][nt], 0, 0, 0);
        if (w < 2) {
#pragma unroll
            for (int nt = 0; nt < 2; ++nt)
#pragma unroll
                for (int j = 0; j < 8; ++j)
                    kp[nt] += bf2f((unsigned short)bfv[nt][j]);
        }
    }

    float* out = KVTp + ((size_t)sp * 64 + bh) * 4096;
#pragma unroll
    for (int mt = 0; mt < 2; ++mt)
#pragma unroll
        for (int nt = 0; nt < 2; ++nt)
#pragma unroll
            for (int i = 0; i < 4; ++i)
                out[(eh + mt * 16 + lg * 4 + i) * 64 + dh + nt * 16 + lr] =
                    acc[mt][nt][i];

    if (w < 2) {
#pragma unroll
        for (int nt = 0; nt < 2; ++nt) {
            kp[nt] += __shfl_xor(kp[nt], 16);
            kp[nt] += __shfl_xor(kp[nt], 32);
        }
        if (lane < 16) {
#pragma unroll
            for (int nt = 0; nt < 2; ++nt)
                Ksump[((size_t)sp * 64 + bh) * 64 + dh + nt * 16 + lane] = kp[nt];
        }
    }
}

// =====================================================================
// Reduce the 16 split-partials once: KVs[bh][4096], Ks[bh][64].
// =====================================================================
__global__ __launch_bounds__(256) void kvred_kernel(
    const float* __restrict__ KVTp, const float* __restrict__ Ksump,
    float* __restrict__ KVs, float* __restrict__ Ks)
{
    const int bh = blockIdx.x;
    const int tid = threadIdx.x;
    for (int i = tid * 4; i < 4096; i += 1024) {
        f32x4 s = {0.0f, 0.0f, 0.0f, 0.0f};
#pragma unroll
        for (int sp = 0; sp < 16; ++sp) {
            f32x4 v = *(const f32x4*)(KVTp + ((size_t)sp * 64 + bh) * 4096 + i);
            s[0] += v[0]; s[1] += v[1]; s[2] += v[2]; s[3] += v[3];
        }
        *(f32x4*)(KVs + (size_t)bh * 4096 + i) = s;
    }
    if (tid < 64) {
        float s = 0.0f;
#pragma unroll
        for (int sp = 0; sp < 16; ++sp)
            s += Ksump[((size_t)sp * 64 + bh) * 64 + tid];
        Ks[bh * 64 + tid] = s;
    }
}

// =====================================================================
// A2[n][h*64+e] = (sum_d Q[n][h*64+d] * KV[d][e]) * invZ(n,h); z fused.
// =====================================================================
__global__ __launch_bounds__(256) void a2_kernel(
    const unsigned short* __restrict__ Q, const float* __restrict__ KVs,
    const float* __restrict__ Ks, unsigned short* __restrict__ A2)
{
    const int m0 = blockIdx.x * 128, h = blockIdx.y;
    const int b = m0 >> 12, bh = (b << 4) + h;
    const int tid = threadIdx.x, lane = tid & 63, w = tid >> 6;
    const int wr = w >> 1, wc = w & 1;
    const int lr = lane & 15, lg = lane >> 4;

    __shared__ float ksum_s[64];
    if (tid < 64) ksum_s[tid] = Ks[bh * 64 + tid];
    __syncthreads();

    f32x4 acc[4][2];
#pragma unroll
    for (int i = 0; i < 4; ++i)
#pragma unroll
        for (int j = 0; j < 2; ++j)
#pragma unroll
            for (int e = 0; e < 4; ++e) acc[i][j][e] = 0.0f;
    float zp[4] = {0.0f, 0.0f, 0.0f, 0.0f};

    const unsigned short* qa = Q + (size_t)(m0 + wr * 64 + lr) * DDIM + h * 64 + lg * 8;
    const float* kvb = KVs + (size_t)bh * 4096 + (wc * 32 + lr) * 64 + lg * 8;

#pragma unroll
    for (int ks = 0; ks < 2; ++ks) {
        short8 af[4];
#pragma unroll
        for (int mt = 0; mt < 4; ++mt)
            af[mt] = *(const short8*)(qa + (size_t)mt * 16 * DDIM + ks * 32);
#pragma unroll
        for (int mt = 0; mt < 4; ++mt)
#pragma unroll
            for (int j = 0; j < 8; ++j)
                zp[mt] += bf2f((unsigned short)af[mt][j]) * ksum_s[ks * 32 + lg * 8 + j];
        short8 bfv[2];
#pragma unroll
        for (int nt = 0; nt < 2; ++nt) {
            const float* p = kvb + nt * 16 * 64 + ks * 32;
            f32x4 v0 = *(const f32x4*)(p);
            f32x4 v1 = *(const f32x4*)(p + 4);
            short8 t;
#pragma unroll
            for (int j = 0; j < 4; ++j) {
                t[j]     = (short)f2bf(v0[j]);
                t[j + 4] = (short)f2bf(v1[j]);
            }
            bfv[nt] = t;
        }
#pragma unroll
        for (int mt = 0; mt < 4; ++mt)
#pragma unroll
            for (int nt = 0; nt < 2; ++nt)
                acc[mt][nt] = __builtin_amdgcn_mfma_f32_16x16x32_bf16(
                    af[mt], bfv[nt], acc[mt][nt], 0, 0, 0);
    }

    float zinv[4];
#pragma unroll
    for (int mt = 0; mt < 4; ++mt) {
        zp[mt] += __shfl_xor(zp[mt], 16);
        zp[mt] += __shfl_xor(zp[mt], 32);
        zinv[mt] = 1.0f / fmaxf(zp[mt], 1e-6f);
    }

#pragma unroll
    for (int mt = 0; mt < 4; ++mt)
#pragma unroll
        for (int nt = 0; nt < 2; ++nt)
#pragma unroll
            for (int i = 0; i < 4; ++i) {
                const int row = m0 + wr * 64 + mt * 16 + lg * 4 + i;
                const int col = h * 64 + wc * 32 + nt * 16 + lr;
                const float zi = __shfl(zinv[mt], lg * 4 + i);
                const float v = acc[mt][nt][i] * zi;
                A2[(size_t)row * DDIM + col] = f2bf(v);
            }
}

// =====================================================================
// host
// =====================================================================
extern "C" void kernel_launch(void* const* d_in, const int* in_sizes, int n_in,
                              void* d_out, int out_size, void* d_ws, size_t ws_size,
                              hipStream_t stream)
{
    const float* query   = (const float*)d_in[0];
    const float* context = (const float*)d_in[1];
    const float* q_w = (const float*)d_in[2];
    const float* q_b = (const float*)d_in[3];
    const float* k_w = (const float*)d_in[4];
    const float* k_b = (const float*)d_in[5];
    const float* v_w = (const float*)d_in[6];
    const float* v_b = (const float*)d_in[7];
    const float* o_w = (const float*)d_in[8];
    const float* o_b = (const float*)d_in[9];
    const float* lnq_g = (const float*)d_in[10];
    const float* lnq_b = (const float*)d_in[11];
    const float* lnk_g = (const float*)d_in[12];
    const float* lnk_b = (const float*)d_in[13];

    char* ws = (char*)d_ws;
    unsigned char* W8   = (unsigned char*)(ws);                     // 0..3 MiB (WQ8,WK8,WV8 fp8 x64)
    unsigned short* WO  = (unsigned short*)(ws + (4u << 20));       // 4..6 bf16
    unsigned char* QLN8 = (unsigned char*)(ws + (8u << 20));        // 8..24 fp8
    unsigned char* CLN8 = (unsigned char*)(ws + (24u << 20));       // 24..40 fp8
    float* KVTp  = (float*)(ws + (40u << 20));                      // 40..56 (16 splits)
    float* Ksump = (float*)(ws + (56u << 20));                      // 256 KiB
    float* KVs   = (float*)(ws + (57u << 20));                      // 1 MiB
    float* Ks    = (float*)(ws + (58u << 20));                      // 16 KiB
    unsigned short* Qm  = (unsigned short*)(ws + (72u << 20));      // 72..104 bf16
    unsigned short* KT  = (unsigned short*)(ws + (104u << 20));     // KVT rows 0-1023
    unsigned short* VT  = (unsigned short*)(ws + (136u << 20));     // KVT rows 1024-2047
    unsigned short* A2  = (unsigned short*)(ws + (8u << 20));       // alias QLN8/CLN8 (dead after qkv)

    ln_kernel<<<8192 + 4096, 256, 0, stream>>>(
        query, context, lnq_g, lnq_b, lnk_g, lnk_b, QLN8, CLN8,
        q_w, k_w, v_w, o_w, W8, WO);
    gemm_qkv8<<<3072, 512, 0, stream>>>(QLN8, CLN8, W8, Qm, KT,
                                        q_b, k_b, v_b);
    kv_kernel<<<dim3(64, 16), 256, 0, stream>>>(VT, KT, KVTp, Ksump);
    kvred_kernel<<<64, 256, 0, stream>>>(KVTp, Ksump, KVs, Ks);
    a2_kernel<<<dim3(128, 16), 256, 0, stream>>>(Qm, KVs, Ks, A2);
    gemm_out256<<<256, 512, 0, stream>>>(A2, WO, (float*)d_out, o_b, query);
}

// Round 16
// 266.352 us; speedup vs baseline: 4.9464x; 2.8574x over previous
//
#include <hip/hip_runtime.h>

#define DEV __device__ __forceinline__

typedef __attribute__((ext_vector_type(8))) short short8;
typedef __attribute__((ext_vector_type(4))) short short4v;
typedef __attribute__((ext_vector_type(4))) float f32x4;

// ---------- bf16 helpers ----------
DEV float bf2f(unsigned short u) { return __uint_as_float(((unsigned int)u) << 16); }
DEV unsigned short f2bf(float f) {
    unsigned int u = __float_as_uint(f);
    u += 0x7FFFu + ((u >> 16) & 1u);   // RNE
    return (unsigned short)(u >> 16);
}

DEV float elu1(float v) { return v > 0.0f ? v + 1.0f : __expf(v); }

// ---------- async global->LDS, 16B per lane ----------
DEV void gload_lds16(const void* g, void* l) {
    __builtin_amdgcn_global_load_lds(
        (__attribute__((address_space(1))) unsigned int*)(g),
        (__attribute__((address_space(3))) unsigned int*)(l),
        16, 0, 0);
}

// Problem constants: B=4, NQ=NC=4096, D=1024, H=16, HD=64
#define NROW 16384
#define DDIM 1024

// =====================================================================
// LayerNorm, wave-per-row (blocks 0..8191, 4 rows each) + weight
// convert (blocks >= 8192). No LDS, no __syncthreads.
// =====================================================================
__global__ __launch_bounds__(256) void ln_kernel(
    const float* __restrict__ query, const float* __restrict__ context,
    const float* __restrict__ lnq_g, const float* __restrict__ lnq_b,
    const float* __restrict__ lnk_g, const float* __restrict__ lnk_b,
    unsigned short* __restrict__ qln, unsigned short* __restrict__ cln,
    const float* __restrict__ q_w, const float* __restrict__ k_w,
    const float* __restrict__ v_w, const float* __restrict__ o_w,
    unsigned short* __restrict__ wout)
{
    const int tid = threadIdx.x;
    if (blockIdx.x >= 8192) {
        const int i = (blockIdx.x - 8192) * 256 + tid;
        const int mat = i >> 18;
        const int idx = (i & 262143) * 4;
        const float* src = mat == 0 ? q_w : mat == 1 ? k_w : mat == 2 ? v_w : o_w;
        f32x4 v = *(const f32x4*)(src + idx);
        short4v o;
#pragma unroll
        for (int j = 0; j < 4; ++j) o[j] = (short)f2bf(v[j]);
        *(short4v*)(wout + (size_t)mat * 1048576 + idx) = o;
        return;
    }

    const int lane = tid & 63, w = tid >> 6;
    const int row = blockIdx.x * 4 + w;          // 0..32767
    const bool isq = row < NROW;
    const int r = isq ? row : row - NROW;
    const float* src = (isq ? query : context) + (size_t)r * DDIM;
    const float* g   = isq ? lnq_g : lnk_g;
    const float* bb  = isq ? lnq_b : lnk_b;
    unsigned short* dst = (isq ? qln : cln) + (size_t)r * DDIM;

    f32x4 x[4];
    float s = 0.0f, sq = 0.0f;
#pragma unroll
    for (int j = 0; j < 4; ++j) {
        x[j] = *(const f32x4*)(src + j * 256 + lane * 4);
#pragma unroll
        for (int e = 0; e < 4; ++e) { s += x[j][e]; sq += x[j][e] * x[j][e]; }
    }
#pragma unroll
    for (int off = 32; off; off >>= 1) {
        s  += __shfl_xor(s, off);
        sq += __shfl_xor(sq, off);
    }
    const float mu  = s * (1.0f / DDIM);
    const float var = sq * (1.0f / DDIM) - mu * mu;
    const float rstd = rsqrtf(var + 1e-5f);

#pragma unroll
    for (int j = 0; j < 4; ++j) {
        f32x4 gv = *(const f32x4*)(g  + j * 256 + lane * 4);
        f32x4 bv = *(const f32x4*)(bb + j * 256 + lane * 4);
        short4v o;
#pragma unroll
        for (int e = 0; e < 4; ++e)
            o[e] = (short)f2bf((x[j][e] - mu) * rstd * gv[e] + bv[e]);
        *(short4v*)(dst + j * 256 + lane * 4) = o;
    }
}

// =====================================================================
// 128x128-tile GEMM core (round-9 verified: 0 conflicts, occ 36%, 736 TF)
// =====================================================================
template <typename EPI>
DEV void gemm128(unsigned short* __restrict__ sA,
                 unsigned short* __restrict__ sB,
                 const unsigned short* __restrict__ Ap,
                 const unsigned short* __restrict__ Bp,
                 int m0, int n0, EPI epi)
{
    const int tid = threadIdx.x;
    const int lane = tid & 63, w = tid >> 6;
    const int wr = w >> 1, wc = w & 1;
    const int lr = lane & 15, lg = lane >> 4;

    const int srow = tid >> 3;
    const int cswz = (tid & 7) ^ (srow & 7);
    const unsigned short* gA0 = Ap + (size_t)(m0 + srow) * 1024 + cswz * 8;
    const unsigned short* gB0 = Bp + (size_t)(n0 + srow) * 1024 + cswz * 8;
    unsigned short* dA = sA + tid * 8;
    unsigned short* dB = sB + tid * 8;

    const int sw0 = ((0 + lg) ^ (lr & 7)) * 8;
    const int sw1 = ((4 + lg) ^ (lr & 7)) * 8;

    f32x4 acc[4][4];
#pragma unroll
    for (int i = 0; i < 4; ++i)
#pragma unroll
        for (int j = 0; j < 4; ++j)
#pragma unroll
            for (int e = 0; e < 4; ++e) acc[i][j][e] = 0.0f;

#define STG8(T)                                                               \
    {                                                                         \
        const int ko = (T) * 64;                                              \
        _Pragma("unroll")                                                     \
        for (int j = 0; j < 4; ++j) {                                         \
            gload_lds16(gA0 + ko + (size_t)j * 32768, dA + j * 2048);         \
            gload_lds16(gB0 + ko + (size_t)j * 32768, dB + j * 2048);         \
        }                                                                     \
    }

    STG8(0);
    for (int t = 0; t < 16; ++t) {
        asm volatile("s_waitcnt vmcnt(0)" ::: "memory");
        __builtin_amdgcn_s_barrier();

        short8 af[4], bf[4];
#pragma unroll
        for (int mt = 0; mt < 4; ++mt)
            af[mt] = *(const short8*)&sA[(wr * 64 + mt * 16 + lr) * 64 + sw0];
#pragma unroll
        for (int nt = 0; nt < 4; ++nt)
            bf[nt] = *(const short8*)&sB[(wc * 64 + nt * 16 + lr) * 64 + sw0];
        __builtin_amdgcn_s_setprio(1);
#pragma unroll
        for (int mt = 0; mt < 4; ++mt)
#pragma unroll
            for (int nt = 0; nt < 4; ++nt)
                acc[mt][nt] = __builtin_amdgcn_mfma_f32_16x16x32_bf16(
                    af[mt], bf[nt], acc[mt][nt], 0, 0, 0);
        __builtin_amdgcn_s_setprio(0);

#pragma unroll
        for (int mt = 0; mt < 4; ++mt)
            af[mt] = *(const short8*)&sA[(wr * 64 + mt * 16 + lr) * 64 + sw1];
#pragma unroll
        for (int nt = 0; nt < 4; ++nt)
            bf[nt] = *(const short8*)&sB[(wc * 64 + nt * 16 + lr) * 64 + sw1];
        asm volatile("s_waitcnt lgkmcnt(0)" ::: "memory");
        __builtin_amdgcn_s_barrier();
        if (t < 15) STG8(t + 1);
        __builtin_amdgcn_s_setprio(1);
#pragma unroll
        for (int mt = 0; mt < 4; ++mt)
#pragma unroll
            for (int nt = 0; nt < 4; ++nt)
                acc[mt][nt] = __builtin_amdgcn_mfma_f32_16x16x32_bf16(
                    af[mt], bf[nt], acc[mt][nt], 0, 0, 0);
        __builtin_amdgcn_s_setprio(0);
    }
#undef STG8

#pragma unroll
    for (int mt = 0; mt < 4; ++mt)
#pragma unroll
        for (int nt = 0; nt < 4; ++nt) {
            const int col = n0 + wc * 64 + nt * 16 + lr;
#pragma unroll
            for (int i = 0; i < 4; ++i) {
                const int row = m0 + wr * 64 + mt * 16 + lg * 4 + i;
                epi(row, col, acc[mt][nt][i]);
            }
        }
}

// ---- merged projections: Q-proj (1024 tiles) + KV-proj (2048 tiles) ----
__global__ __launch_bounds__(256, 4) void gemm_qkv(
    const unsigned short* __restrict__ QLN, const unsigned short* __restrict__ WQ,
    const unsigned short* __restrict__ CLN, const unsigned short* __restrict__ WKV,
    unsigned short* __restrict__ Qm, unsigned short* __restrict__ KVT,
    const float* __restrict__ q_b, const float* __restrict__ k_b,
    const float* __restrict__ v_b)
{
    __shared__ __attribute__((aligned(16))) unsigned short sA[128 * 64];
    __shared__ __attribute__((aligned(16))) unsigned short sB[128 * 64];

    const int bid = blockIdx.x;                  // 3072 blocks
    const int l = (bid & 7) * 384 + (bid >> 3);  // XCD-chunked

    if (l < 1024) {
        const int m0 = (l >> 3) * 128, n0 = (l & 7) * 128;
        gemm128(sA, sB, QLN, WQ, m0, n0,
            [&](int row, int col, float v) {
                v = elu1(v + q_b[col]);
                Qm[(size_t)row * 1024 + col] = f2bf(v);
            });
    } else {
        const int r = l - 1024;                  // 0..2047
        const int m0 = (r & 15) * 128, n0 = (r >> 4) * 128;
        gemm128(sA, sB, WKV, CLN, m0, n0,
            [&](int row, int col, float v) {
                if (row < 1024) v = elu1(v + k_b[row]);
                else            v = v + v_b[row - 1024];
                KVT[(size_t)row * NROW + col] = f2bf(v);
            });
    }
}

// =====================================================================
// O-projection: round-5 deep-pipelined 256x256/BK=64/8-wave kernel.
// =====================================================================
__global__ __launch_bounds__(512, 2) void gemm_out256(
    const unsigned short* __restrict__ A, const unsigned short* __restrict__ Bm,
    float* __restrict__ Cout, const float* __restrict__ bias,
    const float* __restrict__ resid)
{
    __shared__ __attribute__((aligned(16))) unsigned short smem[65536];
    unsigned short* sAb = smem;           // 2 x 16384
    unsigned short* sBb = smem + 32768;   // 2 x 16384

    const int bid = blockIdx.x;           // 256 blocks
    const int l = (bid & 7) * 32 + (bid >> 3);
    const int m0 = (l >> 2) * 256, n0 = (l & 3) * 256;

    const int tid = threadIdx.x;
    const int lane = tid & 63, w = tid >> 6;
    const int wr = w >> 2, wc = w & 3;          // 2 x 4 wave grid
    const int lr = lane & 15, lg = lane >> 4;

    const int srow = tid >> 3;
    const int cswz = (tid & 7) ^ (srow & 7);
    const unsigned short* gA0 = A  + (size_t)(m0 + srow) * 1024 + cswz * 8;
    const unsigned short* gB0 = Bm + (size_t)(n0 + srow) * 1024 + cswz * 8;

    const int sw0 = ((0 + lg) ^ (lr & 7)) * 8;
    const int sw1 = ((4 + lg) ^ (lr & 7)) * 8;

    f32x4 acc[8][4];
#pragma unroll
    for (int i = 0; i < 8; ++i)
#pragma unroll
        for (int j = 0; j < 4; ++j)
#pragma unroll
            for (int e = 0; e < 4; ++e) acc[i][j][e] = 0.0f;

#define STG(GP, SP, T)                                                        \
    {                                                                         \
        const unsigned short* g = (GP) + (T) * 64;                            \
        unsigned short* d = (SP) + ((T) & 1) * 16384 + tid * 8;               \
        _Pragma("unroll")                                                     \
        for (int L = 0; L < 4; ++L)                                           \
            gload_lds16(g + (size_t)L * 65536, d + L * 4096);                 \
    }

    STG(gB0, sBb, 0); STG(gA0, sAb, 0); STG(gB0, sBb, 1); STG(gA0, sAb, 1);
    asm volatile("s_waitcnt vmcnt(8)" ::: "memory");
    __builtin_amdgcn_s_barrier();

    short8 bvl[2][2];
#pragma unroll
    for (int nt = 0; nt < 2; ++nt) {
        const int rb = (wc * 64 + nt * 16 + lr) * 64;
        bvl[nt][0] = *(const short8*)&sBb[rb + sw0];
        bvl[nt][1] = *(const short8*)&sBb[rb + sw1];
    }

    for (int t = 0; t < 16; ++t) {
        const unsigned short* bA = sAb + (t & 1) * 16384;
        const unsigned short* bB = sBb + (t & 1) * 16384;
        const unsigned short* bBn = sBb + ((t + 1) & 1) * 16384;
        short8 afl[4][2], afh[4][2], bvh[2][2], bvln[2][2];

        // ---- P0 ----
#pragma unroll
        for (int mt = 0; mt < 4; ++mt) {
            const int ra = (wr * 128 + mt * 16 + lr) * 64;
            afl[mt][0] = *(const short8*)&bA[ra + sw0];
            afl[mt][1] = *(const short8*)&bA[ra + sw1];
        }
#pragma unroll
        for (int mt = 0; mt < 4; ++mt) {
            const int ra = (wr * 128 + (mt + 4) * 16 + lr) * 64;
            afh[mt][0] = *(const short8*)&bA[ra + sw0];
            afh[mt][1] = *(const short8*)&bA[ra + sw1];
        }
        asm volatile("s_waitcnt lgkmcnt(8)" ::: "memory");
        __builtin_amdgcn_s_setprio(1);
#pragma unroll
        for (int kk = 0; kk < 2; ++kk)
#pragma unroll
            for (int mt = 0; mt < 4; ++mt)
#pragma unroll
                for (int nt = 0; nt < 2; ++nt)
                    acc[mt][nt] = __builtin_amdgcn_mfma_f32_16x16x32_bf16(
                        afl[mt][kk], bvl[nt][kk], acc[mt][nt], 0, 0, 0);
        __builtin_amdgcn_s_setprio(0);
        __builtin_amdgcn_s_barrier();

        // ---- P1 ----
#pragma unroll
        for (int nt = 0; nt < 2; ++nt) {
            const int rb = (wc * 64 + (nt + 2) * 16 + lr) * 64;
            bvh[nt][0] = *(const short8*)&bB[rb + sw0];
            bvh[nt][1] = *(const short8*)&bB[rb + sw1];
        }
        asm volatile("s_waitcnt lgkmcnt(4)" ::: "memory");
        __builtin_amdgcn_s_setprio(1);
#pragma unroll
        for (int kk = 0; kk < 2; ++kk)
#pragma unroll
            for (int mt = 0; mt < 4; ++mt)
#pragma unroll
                for (int nt = 0; nt < 2; ++nt)
                    acc[mt + 4][nt] = __builtin_amdgcn_mfma_f32_16x16x32_bf16(
                        afh[mt][kk], bvl[nt][kk], acc[mt + 4][nt], 0, 0, 0);
        __builtin_amdgcn_s_setprio(0);
        asm volatile("s_waitcnt vmcnt(0)" ::: "memory");
        __builtin_amdgcn_s_barrier();

        // ---- P2 ----
        if (t < 15) {
#pragma unroll
            for (int nt = 0; nt < 2; ++nt) {
                const int rb = (wc * 64 + nt * 16 + lr) * 64;
                bvln[nt][0] = *(const short8*)&bBn[rb + sw0];
                bvln[nt][1] = *(const short8*)&bBn[rb + sw1];
            }
        }
        if (t + 2 < 16) STG(gA0, sAb, t + 2);
        if (t < 15) asm volatile("s_waitcnt lgkmcnt(4)" ::: "memory");
        else        asm volatile("s_waitcnt lgkmcnt(0)" ::: "memory");
        __builtin_amdgcn_s_setprio(1);
#pragma unroll
        for (int kk = 0; kk < 2; ++kk)
#pragma unroll
            for (int mt = 0; mt < 4; ++mt)
#pragma unroll
                for (int nt = 0; nt < 2; ++nt)
                    acc[mt + 4][nt + 2] = __builtin_amdgcn_mfma_f32_16x16x32_bf16(
                        afh[mt][kk], bvh[nt][kk], acc[mt + 4][nt + 2], 0, 0, 0);
        __builtin_amdgcn_s_setprio(0);
        __builtin_amdgcn_s_barrier();

        // ---- P3 ----
        if (t + 2 < 16) STG(gB0, sBb, t + 2);
        __builtin_amdgcn_s_setprio(1);
#pragma unroll
        for (int kk = 0; kk < 2; ++kk)
#pragma unroll
            for (int mt = 0; mt < 4; ++mt)
#pragma unroll
                for (int nt = 0; nt < 2; ++nt)
                    acc[mt][nt + 2] = __builtin_amdgcn_mfma_f32_16x16x32_bf16(
                        afl[mt][kk], bvh[nt][kk], acc[mt][nt + 2], 0, 0, 0);
        __builtin_amdgcn_s_setprio(0);

        if (t < 15) {
#pragma unroll
            for (int nt = 0; nt < 2; ++nt) {
                bvl[nt][0] = bvln[nt][0];
                bvl[nt][1] = bvln[nt][1];
            }
        }
    }
#undef STG

#pragma unroll
    for (int mt = 0; mt < 8; ++mt) {
#pragma unroll
        for (int nt = 0; nt < 4; ++nt) {
            const int col = n0 + wc * 64 + nt * 16 + lr;
#pragma unroll
            for (int i = 0; i < 4; ++i) {
                const int row = m0 + wr * 128 + mt * 16 + lg * 4 + i;
                Cout[(size_t)row * 1024 + col] =
                    acc[mt][nt][i] + bias[col] + resid[(size_t)row * 1024 + col];
            }
        }
    }
}

// =====================================================================
// KV partials + Ksum partials; quadrant-per-wave, 16 n-splits.
// =====================================================================
__global__ __launch_bounds__(256) void kv_kernel(
    const unsigned short* __restrict__ VT, const unsigned short* __restrict__ KT,
    float* __restrict__ KVTp, float* __restrict__ Ksump)
{
    const int bh = blockIdx.x, sp = blockIdx.y;   // 64 x 16
    const int b = bh >> 4, h = bh & 15;
    const int tid = threadIdx.x, lane = tid & 63, w = tid >> 6;
    const int lr = lane & 15, lg = lane >> 4;
    const int eh = (w >> 1) * 32, dh = (w & 1) * 32;

    f32x4 acc[2][2];
#pragma unroll
    for (int i = 0; i < 2; ++i)
#pragma unroll
        for (int j = 0; j < 2; ++j)
#pragma unroll
            for (int e = 0; e < 4; ++e) acc[i][j][e] = 0.0f;
    float kp[2] = {0.0f, 0.0f};

    const size_t colbase = (size_t)b * 4096 + sp * 256 + lg * 8;
    const unsigned short* va = VT + (size_t)(h * 64 + eh + lr) * NROW + colbase;
    const unsigned short* ka = KT + (size_t)(h * 64 + dh + lr) * NROW + colbase;

    for (int ks = 0; ks < 8; ++ks) {
        short8 af[2], bfv[2];
        af[0]  = *(const short8*)(va + ks * 32);
        af[1]  = *(const short8*)(va + (size_t)16 * NROW + ks * 32);
        bfv[0] = *(const short8*)(ka + ks * 32);
        bfv[1] = *(const short8*)(ka + (size_t)16 * NROW + ks * 32);
#pragma unroll
        for (int mt = 0; mt < 2; ++mt)
#pragma unroll
            for (int nt = 0; nt < 2; ++nt)
                acc[mt][nt] = __builtin_amdgcn_mfma_f32_16x16x32_bf16(
                    af[mt], bfv[nt], acc[mt][nt], 0, 0, 0);
        if (w < 2) {
#pragma unroll
            for (int nt = 0; nt < 2; ++nt)
#pragma unroll
                for (int j = 0; j < 8; ++j)
                    kp[nt] += bf2f((unsigned short)bfv[nt][j]);
        }
    }

    float* out = KVTp + ((size_t)sp * 64 + bh) * 4096;
#pragma unroll
    for (int mt = 0; mt < 2; ++mt)
#pragma unroll
        for (int nt = 0; nt < 2; ++nt)
#pragma unroll
            for (int i = 0; i < 4; ++i)
                out[(eh + mt * 16 + lg * 4 + i) * 64 + dh + nt * 16 + lr] =
                    acc[mt][nt][i];

    if (w < 2) {
#pragma unroll
        for (int nt = 0; nt < 2; ++nt) {
            kp[nt] += __shfl_xor(kp[nt], 16);
            kp[nt] += __shfl_xor(kp[nt], 32);
        }
        if (lane < 16) {
#pragma unroll
            for (int nt = 0; nt < 2; ++nt)
                Ksump[((size_t)sp * 64 + bh) * 64 + dh + nt * 16 + lane] = kp[nt];
        }
    }
}

// =====================================================================
// Reduce the 16 split-partials once: KVs[bh][4096], Ks[bh][64].
// =====================================================================
__global__ __launch_bounds__(256) void kvred_kernel(
    const float* __restrict__ KVTp, const float* __restrict__ Ksump,
    float* __restrict__ KVs, float* __restrict__ Ks)
{
    const int bh = blockIdx.x;
    const int tid = threadIdx.x;
    for (int i = tid * 4; i < 4096; i += 1024) {
        f32x4 s = {0.0f, 0.0f, 0.0f, 0.0f};
#pragma unroll
        for (int sp = 0; sp < 16; ++sp) {
            f32x4 v = *(const f32x4*)(KVTp + ((size_t)sp * 64 + bh) * 4096 + i);
            s[0] += v[0]; s[1] += v[1]; s[2] += v[2]; s[3] += v[3];
        }
        *(f32x4*)(KVs + (size_t)bh * 4096 + i) = s;
    }
    if (tid < 64) {
        float s = 0.0f;
#pragma unroll
        for (int sp = 0; sp < 16; ++sp)
            s += Ksump[((size_t)sp * 64 + bh) * 64 + tid];
        Ks[bh * 64 + tid] = s;
    }
}

// =====================================================================
// A2[n][h*64+e] = (sum_d Q[n][h*64+d] * KV[d][e]) * invZ(n,h); z fused.
// =====================================================================
__global__ __launch_bounds__(256) void a2_kernel(
    const unsigned short* __restrict__ Q, const float* __restrict__ KVs,
    const float* __restrict__ Ks, unsigned short* __restrict__ A2)
{
    const int m0 = blockIdx.x * 128, h = blockIdx.y;
    const int b = m0 >> 12, bh = (b << 4) + h;
    const int tid = threadIdx.x, lane = tid & 63, w = tid >> 6;
    const int wr = w >> 1, wc = w & 1;
    const int lr = lane & 15, lg = lane >> 4;

    __shared__ float ksum_s[64];
    if (tid < 64) ksum_s[tid] = Ks[bh * 64 + tid];
    __syncthreads();

    f32x4 acc[4][2];
#pragma unroll
    for (int i = 0; i < 4; ++i)
#pragma unroll
        for (int j = 0; j < 2; ++j)
#pragma unroll
            for (int e = 0; e < 4; ++e) acc[i][j][e] = 0.0f;
    float zp[4] = {0.0f, 0.0f, 0.0f, 0.0f};

    const unsigned short* qa = Q + (size_t)(m0 + wr * 64 + lr) * DDIM + h * 64 + lg * 8;
    const float* kvb = KVs + (size_t)bh * 4096 + (wc * 32 + lr) * 64 + lg * 8;

#pragma unroll
    for (int ks = 0; ks < 2; ++ks) {
        short8 af[4];
#pragma unroll
        for (int mt = 0; mt < 4; ++mt)
            af[mt] = *(const short8*)(qa + (size_t)mt * 16 * DDIM + ks * 32);
#pragma unroll
        for (int mt = 0; mt < 4; ++mt)
#pragma unroll
            for (int j = 0; j < 8; ++j)
                zp[mt] += bf2f((unsigned short)af[mt][j]) * ksum_s[ks * 32 + lg * 8 + j];
        short8 bfv[2];
#pragma unroll
        for (int nt = 0; nt < 2; ++nt) {
            const float* p = kvb + nt * 16 * 64 + ks * 32;
            f32x4 v0 = *(const f32x4*)(p);
            f32x4 v1 = *(const f32x4*)(p + 4);
            short8 t;
#pragma unroll
            for (int j = 0; j < 4; ++j) {
                t[j]     = (short)f2bf(v0[j]);
                t[j + 4] = (short)f2bf(v1[j]);
            }
            bfv[nt] = t;
        }
#pragma unroll
        for (int mt = 0; mt < 4; ++mt)
#pragma unroll
            for (int nt = 0; nt < 2; ++nt)
                acc[mt][nt] = __builtin_amdgcn_mfma_f32_16x16x32_bf16(
                    af[mt], bfv[nt], acc[mt][nt], 0, 0, 0);
    }

    float zinv[4];
#pragma unroll
    for (int mt = 0; mt < 4; ++mt) {
        zp[mt] += __shfl_xor(zp[mt], 16);
        zp[mt] += __shfl_xor(zp[mt], 32);
        zinv[mt] = 1.0f / fmaxf(zp[mt], 1e-6f);
    }

#pragma unroll
    for (int mt = 0; mt < 4; ++mt)
#pragma unroll
        for (int nt = 0; nt < 2; ++nt)
#pragma unroll
            for (int i = 0; i < 4; ++i) {
                const int row = m0 + wr * 64 + mt * 16 + lg * 4 + i;
                const int col = h * 64 + wc * 32 + nt * 16 + lr;
                const float zi = __shfl(zinv[mt], lg * 4 + i);
                const float v = acc[mt][nt][i] * zi;
                A2[(size_t)row * DDIM + col] = f2bf(v);
            }
}

// =====================================================================
// host
// =====================================================================
extern "C" void kernel_launch(void* const* d_in, const int* in_sizes, int n_in,
                              void* d_out, int out_size, void* d_ws, size_t ws_size,
                              hipStream_t stream)
{
    const float* query   = (const float*)d_in[0];
    const float* context = (const float*)d_in[1];
    const float* q_w = (const float*)d_in[2];
    const float* q_b = (const float*)d_in[3];
    const float* k_w = (const float*)d_in[4];
    const float* k_b = (const float*)d_in[5];
    const float* v_w = (const float*)d_in[6];
    const float* v_b = (const float*)d_in[7];
    const float* o_w = (const float*)d_in[8];
    const float* o_b = (const float*)d_in[9];
    const float* lnq_g = (const float*)d_in[10];
    const float* lnq_b = (const float*)d_in[11];
    const float* lnk_g = (const float*)d_in[12];
    const float* lnk_b = (const float*)d_in[13];

    char* ws = (char*)d_ws;
    unsigned short* WQ  = (unsigned short*)(ws);                    // 0..2 MiB
    unsigned short* WKV = (unsigned short*)(ws + (2u << 20));       // 2..6
    unsigned short* WO  = (unsigned short*)(ws + (6u << 20));       // 6..8
    unsigned short* QLN = (unsigned short*)(ws + (8u << 20));       // 8..40
    unsigned short* CLN = (unsigned short*)(ws + (40u << 20));      // 40..72 (dead after qkv)
    unsigned short* Qm  = (unsigned short*)(ws + (72u << 20));      // 72..104
    unsigned short* KT  = (unsigned short*)(ws + (104u << 20));     // KVT rows 0-1023
    unsigned short* VT  = (unsigned short*)(ws + (136u << 20));     // KVT rows 1024-2047
    float* KVTp  = (float*)(ws + (40u << 20));                      // 16 MiB (16 splits)
    float* Ksump = (float*)(ws + (56u << 20));                      // 256 KiB
    float* KVs   = (float*)(ws + (57u << 20));                      // 1 MiB
    float* Ks    = (float*)(ws + (58u << 20));                      // 16 KiB
    unsigned short* A2 = QLN;                                       // alias (QLN dead)

    ln_kernel<<<8192 + 4096, 256, 0, stream>>>(
        query, context, lnq_g, lnq_b, lnk_g, lnk_b, QLN, CLN,
        q_w, k_w, v_w, o_w, WQ);
    gemm_qkv<<<3072, 256, 0, stream>>>(QLN, WQ, CLN, WKV, Qm, KT,
                                       q_b, k_b, v_b);
    kv_kernel<<<dim3(64, 16), 256, 0, stream>>>(VT, KT, KVTp, Ksump);
    kvred_kernel<<<64, 256, 0, stream>>>(KVTp, Ksump, KVs, Ks);
    a2_kernel<<<dim3(128, 16), 256, 0, stream>>>(Qm, KVs, Ks, A2);
    gemm_out256<<<256, 512, 0, stream>>>(A2, WO, (float*)d_out, o_b, query);
}

// Round 17
// 265.882 us; speedup vs baseline: 4.9552x; 1.0018x over previous
//
#include <hip/hip_runtime.h>

#define DEV __device__ __forceinline__

typedef __attribute__((ext_vector_type(8))) short short8;
typedef __attribute__((ext_vector_type(4))) short short4v;
typedef __attribute__((ext_vector_type(4))) float f32x4;

// ---------- bf16 helpers ----------
DEV float bf2f(unsigned short u) { return __uint_as_float(((unsigned int)u) << 16); }
DEV unsigned short f2bf(float f) {
    unsigned int u = __float_as_uint(f);
    u += 0x7FFFu + ((u >> 16) & 1u);   // RNE
    return (unsigned short)(u >> 16);
}

DEV float elu1(float v) { return v > 0.0f ? v + 1.0f : __expf(v); }

// ---------- async global->LDS, 16B per lane ----------
DEV void gload_lds16(const void* g, void* l) {
    __builtin_amdgcn_global_load_lds(
        (__attribute__((address_space(1))) unsigned int*)(g),
        (__attribute__((address_space(3))) unsigned int*)(l),
        16, 0, 0);
}

// Problem constants: B=4, NQ=NC=4096, D=1024, H=16, HD=64
#define NROW 16384
#define DDIM 1024

// =====================================================================
// LayerNorm, wave-per-row (blocks 0..8191, 4 rows each) + weight
// convert (blocks >= 8192). No LDS, no __syncthreads.
// =====================================================================
__global__ __launch_bounds__(256) void ln_kernel(
    const float* __restrict__ query, const float* __restrict__ context,
    const float* __restrict__ lnq_g, const float* __restrict__ lnq_b,
    const float* __restrict__ lnk_g, const float* __restrict__ lnk_b,
    unsigned short* __restrict__ qln, unsigned short* __restrict__ cln,
    const float* __restrict__ q_w, const float* __restrict__ k_w,
    const float* __restrict__ v_w, const float* __restrict__ o_w,
    unsigned short* __restrict__ wout)
{
    const int tid = threadIdx.x;
    if (blockIdx.x >= 8192) {
        const int i = (blockIdx.x - 8192) * 256 + tid;
        const int mat = i >> 18;
        const int idx = (i & 262143) * 4;
        const float* src = mat == 0 ? q_w : mat == 1 ? k_w : mat == 2 ? v_w : o_w;
        f32x4 v = *(const f32x4*)(src + idx);
        short4v o;
#pragma unroll
        for (int j = 0; j < 4; ++j) o[j] = (short)f2bf(v[j]);
        *(short4v*)(wout + (size_t)mat * 1048576 + idx) = o;
        return;
    }

    const int lane = tid & 63, w = tid >> 6;
    const int row = blockIdx.x * 4 + w;          // 0..32767
    const bool isq = row < NROW;
    const int r = isq ? row : row - NROW;
    const float* src = (isq ? query : context) + (size_t)r * DDIM;
    const float* g   = isq ? lnq_g : lnk_g;
    const float* bb  = isq ? lnq_b : lnk_b;
    unsigned short* dst = (isq ? qln : cln) + (size_t)r * DDIM;

    f32x4 x[4];
    float s = 0.0f, sq = 0.0f;
#pragma unroll
    for (int j = 0; j < 4; ++j) {
        x[j] = *(const f32x4*)(src + j * 256 + lane * 4);
#pragma unroll
        for (int e = 0; e < 4; ++e) { s += x[j][e]; sq += x[j][e] * x[j][e]; }
    }
#pragma unroll
    for (int off = 32; off; off >>= 1) {
        s  += __shfl_xor(s, off);
        sq += __shfl_xor(sq, off);
    }
    const float mu  = s * (1.0f / DDIM);
    const float var = sq * (1.0f / DDIM) - mu * mu;
    const float rstd = rsqrtf(var + 1e-5f);

#pragma unroll
    for (int j = 0; j < 4; ++j) {
        f32x4 gv = *(const f32x4*)(g  + j * 256 + lane * 4);
        f32x4 bv = *(const f32x4*)(bb + j * 256 + lane * 4);
        short4v o;
#pragma unroll
        for (int e = 0; e < 4; ++e)
            o[e] = (short)f2bf((x[j][e] - mu) * rstd * gv[e] + bv[e]);
        *(short4v*)(dst + j * 256 + lane * 4) = o;
    }
}

// =====================================================================
// 128x128-tile GEMM core (round-9 verified: 0 conflicts, occ 36%, 736 TF)
// =====================================================================
template <typename EPI>
DEV void gemm128(unsigned short* __restrict__ sA,
                 unsigned short* __restrict__ sB,
                 const unsigned short* __restrict__ Ap,
                 const unsigned short* __restrict__ Bp,
                 int m0, int n0, EPI epi)
{
    const int tid = threadIdx.x;
    const int lane = tid & 63, w = tid >> 6;
    const int wr = w >> 1, wc = w & 1;
    const int lr = lane & 15, lg = lane >> 4;

    const int srow = tid >> 3;
    const int cswz = (tid & 7) ^ (srow & 7);
    const unsigned short* gA0 = Ap + (size_t)(m0 + srow) * 1024 + cswz * 8;
    const unsigned short* gB0 = Bp + (size_t)(n0 + srow) * 1024 + cswz * 8;
    unsigned short* dA = sA + tid * 8;
    unsigned short* dB = sB + tid * 8;

    const int sw0 = ((0 + lg) ^ (lr & 7)) * 8;
    const int sw1 = ((4 + lg) ^ (lr & 7)) * 8;

    f32x4 acc[4][4];
#pragma unroll
    for (int i = 0; i < 4; ++i)
#pragma unroll
        for (int j = 0; j < 4; ++j)
#pragma unroll
            for (int e = 0; e < 4; ++e) acc[i][j][e] = 0.0f;

#define STG8(T)                                                               \
    {                                                                         \
        const int ko = (T) * 64;                                              \
        _Pragma("unroll")                                                     \
        for (int j = 0; j < 4; ++j) {                                         \
            gload_lds16(gA0 + ko + (size_t)j * 32768, dA + j * 2048);         \
            gload_lds16(gB0 + ko + (size_t)j * 32768, dB + j * 2048);         \
        }                                                                     \
    }

    STG8(0);
    for (int t = 0; t < 16; ++t) {
        asm volatile("s_waitcnt vmcnt(0)" ::: "memory");
        __builtin_amdgcn_s_barrier();

        short8 af[4], bf[4];
#pragma unroll
        for (int mt = 0; mt < 4; ++mt)
            af[mt] = *(const short8*)&sA[(wr * 64 + mt * 16 + lr) * 64 + sw0];
#pragma unroll
        for (int nt = 0; nt < 4; ++nt)
            bf[nt] = *(const short8*)&sB[(wc * 64 + nt * 16 + lr) * 64 + sw0];
        __builtin_amdgcn_s_setprio(1);
#pragma unroll
        for (int mt = 0; mt < 4; ++mt)
#pragma unroll
            for (int nt = 0; nt < 4; ++nt)
                acc[mt][nt] = __builtin_amdgcn_mfma_f32_16x16x32_bf16(
                    af[mt], bf[nt], acc[mt][nt], 0, 0, 0);
        __builtin_amdgcn_s_setprio(0);

#pragma unroll
        for (int mt = 0; mt < 4; ++mt)
            af[mt] = *(const short8*)&sA[(wr * 64 + mt * 16 + lr) * 64 + sw1];
#pragma unroll
        for (int nt = 0; nt < 4; ++nt)
            bf[nt] = *(const short8*)&sB[(wc * 64 + nt * 16 + lr) * 64 + sw1];
        asm volatile("s_waitcnt lgkmcnt(0)" ::: "memory");
        __builtin_amdgcn_s_barrier();
        if (t < 15) STG8(t + 1);
        __builtin_amdgcn_s_setprio(1);
#pragma unroll
        for (int mt = 0; mt < 4; ++mt)
#pragma unroll
            for (int nt = 0; nt < 4; ++nt)
                acc[mt][nt] = __builtin_amdgcn_mfma_f32_16x16x32_bf16(
                    af[mt], bf[nt], acc[mt][nt], 0, 0, 0);
        __builtin_amdgcn_s_setprio(0);
    }
#undef STG8

#pragma unroll
    for (int mt = 0; mt < 4; ++mt)
#pragma unroll
        for (int nt = 0; nt < 4; ++nt) {
            const int col = n0 + wc * 64 + nt * 16 + lr;
#pragma unroll
            for (int i = 0; i < 4; ++i) {
                const int row = m0 + wr * 64 + mt * 16 + lg * 4 + i;
                epi(row, col, acc[mt][nt][i]);
            }
        }
}

// ---- merged projections: Q-proj (1024 tiles) + KV-proj (2048 tiles) ----
__global__ __launch_bounds__(256, 4) void gemm_qkv(
    const unsigned short* __restrict__ QLN, const unsigned short* __restrict__ WQ,
    const unsigned short* __restrict__ CLN, const unsigned short* __restrict__ WKV,
    unsigned short* __restrict__ Qm, unsigned short* __restrict__ KVT,
    const float* __restrict__ q_b, const float* __restrict__ k_b,
    const float* __restrict__ v_b)
{
    __shared__ __attribute__((aligned(16))) unsigned short sA[128 * 64];
    __shared__ __attribute__((aligned(16))) unsigned short sB[128 * 64];

    const int bid = blockIdx.x;                  // 3072 blocks
    const int l = (bid & 7) * 384 + (bid >> 3);  // XCD-chunked

    if (l < 1024) {
        const int m0 = (l >> 3) * 128, n0 = (l & 7) * 128;
        gemm128(sA, sB, QLN, WQ, m0, n0,
            [&](int row, int col, float v) {
                v = elu1(v + q_b[col]);
                Qm[(size_t)row * 1024 + col] = f2bf(v);
            });
    } else {
        const int r = l - 1024;                  // 0..2047
        const int m0 = (r & 15) * 128, n0 = (r >> 4) * 128;
        gemm128(sA, sB, WKV, CLN, m0, n0,
            [&](int row, int col, float v) {
                if (row < 1024) v = elu1(v + k_b[row]);
                else            v = v + v_b[row - 1024];
                KVT[(size_t)row * NROW + col] = f2bf(v);
            });
    }
}

// =====================================================================
// O-projection: round-5 deep-pipelined 256x256/BK=64/8-wave kernel.
// =====================================================================
__global__ __launch_bounds__(512, 2) void gemm_out256(
    const unsigned short* __restrict__ A, const unsigned short* __restrict__ Bm,
    float* __restrict__ Cout, const float* __restrict__ bias,
    const float* __restrict__ resid)
{
    __shared__ __attribute__((aligned(16))) unsigned short smem[65536];
    unsigned short* sAb = smem;           // 2 x 16384
    unsigned short* sBb = smem + 32768;   // 2 x 16384

    const int bid = blockIdx.x;           // 256 blocks
    const int l = (bid & 7) * 32 + (bid >> 3);
    const int m0 = (l >> 2) * 256, n0 = (l & 3) * 256;

    const int tid = threadIdx.x;
    const int lane = tid & 63, w = tid >> 6;
    const int wr = w >> 2, wc = w & 3;          // 2 x 4 wave grid
    const int lr = lane & 15, lg = lane >> 4;

    const int srow = tid >> 3;
    const int cswz = (tid & 7) ^ (srow & 7);
    const unsigned short* gA0 = A  + (size_t)(m0 + srow) * 1024 + cswz * 8;
    const unsigned short* gB0 = Bm + (size_t)(n0 + srow) * 1024 + cswz * 8;

    const int sw0 = ((0 + lg) ^ (lr & 7)) * 8;
    const int sw1 = ((4 + lg) ^ (lr & 7)) * 8;

    f32x4 acc[8][4];
#pragma unroll
    for (int i = 0; i < 8; ++i)
#pragma unroll
        for (int j = 0; j < 4; ++j)
#pragma unroll
            for (int e = 0; e < 4; ++e) acc[i][j][e] = 0.0f;

#define STG(GP, SP, T)                                                        \
    {                                                                         \
        const unsigned short* g = (GP) + (T) * 64;                            \
        unsigned short* d = (SP) + ((T) & 1) * 16384 + tid * 8;               \
        _Pragma("unroll")                                                     \
        for (int L = 0; L < 4; ++L)                                           \
            gload_lds16(g + (size_t)L * 65536, d + L * 4096);                 \
    }

    STG(gB0, sBb, 0); STG(gA0, sAb, 0); STG(gB0, sBb, 1); STG(gA0, sAb, 1);
    asm volatile("s_waitcnt vmcnt(8)" ::: "memory");
    __builtin_amdgcn_s_barrier();

    short8 bvl[2][2];
#pragma unroll
    for (int nt = 0; nt < 2; ++nt) {
        const int rb = (wc * 64 + nt * 16 + lr) * 64;
        bvl[nt][0] = *(const short8*)&sBb[rb + sw0];
        bvl[nt][1] = *(const short8*)&sBb[rb + sw1];
    }

    for (int t = 0; t < 16; ++t) {
        const unsigned short* bA = sAb + (t & 1) * 16384;
        const unsigned short* bB = sBb + (t & 1) * 16384;
        const unsigned short* bBn = sBb + ((t + 1) & 1) * 16384;
        short8 afl[4][2], afh[4][2], bvh[2][2], bvln[2][2];

        // ---- P0 ----
#pragma unroll
        for (int mt = 0; mt < 4; ++mt) {
            const int ra = (wr * 128 + mt * 16 + lr) * 64;
            afl[mt][0] = *(const short8*)&bA[ra + sw0];
            afl[mt][1] = *(const short8*)&bA[ra + sw1];
        }
#pragma unroll
        for (int mt = 0; mt < 4; ++mt) {
            const int ra = (wr * 128 + (mt + 4) * 16 + lr) * 64;
            afh[mt][0] = *(const short8*)&bA[ra + sw0];
            afh[mt][1] = *(const short8*)&bA[ra + sw1];
        }
        asm volatile("s_waitcnt lgkmcnt(8)" ::: "memory");
        __builtin_amdgcn_s_setprio(1);
#pragma unroll
        for (int kk = 0; kk < 2; ++kk)
#pragma unroll
            for (int mt = 0; mt < 4; ++mt)
#pragma unroll
                for (int nt = 0; nt < 2; ++nt)
                    acc[mt][nt] = __builtin_amdgcn_mfma_f32_16x16x32_bf16(
                        afl[mt][kk], bvl[nt][kk], acc[mt][nt], 0, 0, 0);
        __builtin_amdgcn_s_setprio(0);
        __builtin_amdgcn_s_barrier();

        // ---- P1 ----
#pragma unroll
        for (int nt = 0; nt < 2; ++nt) {
            const int rb = (wc * 64 + (nt + 2) * 16 + lr) * 64;
            bvh[nt][0] = *(const short8*)&bB[rb + sw0];
            bvh[nt][1] = *(const short8*)&bB[rb + sw1];
        }
        asm volatile("s_waitcnt lgkmcnt(4)" ::: "memory");
        __builtin_amdgcn_s_setprio(1);
#pragma unroll
        for (int kk = 0; kk < 2; ++kk)
#pragma unroll
            for (int mt = 0; mt < 4; ++mt)
#pragma unroll
                for (int nt = 0; nt < 2; ++nt)
                    acc[mt + 4][nt] = __builtin_amdgcn_mfma_f32_16x16x32_bf16(
                        afh[mt][kk], bvl[nt][kk], acc[mt + 4][nt], 0, 0, 0);
        __builtin_amdgcn_s_setprio(0);
        asm volatile("s_waitcnt vmcnt(0)" ::: "memory");
        __builtin_amdgcn_s_barrier();

        // ---- P2 ----
        if (t < 15) {
#pragma unroll
            for (int nt = 0; nt < 2; ++nt) {
                const int rb = (wc * 64 + nt * 16 + lr) * 64;
                bvln[nt][0] = *(const short8*)&bBn[rb + sw0];
                bvln[nt][1] = *(const short8*)&bBn[rb + sw1];
            }
        }
        if (t + 2 < 16) STG(gA0, sAb, t + 2);
        if (t < 15) asm volatile("s_waitcnt lgkmcnt(4)" ::: "memory");
        else        asm volatile("s_waitcnt lgkmcnt(0)" ::: "memory");
        __builtin_amdgcn_s_setprio(1);
#pragma unroll
        for (int kk = 0; kk < 2; ++kk)
#pragma unroll
            for (int mt = 0; mt < 4; ++mt)
#pragma unroll
                for (int nt = 0; nt < 2; ++nt)
                    acc[mt + 4][nt + 2] = __builtin_amdgcn_mfma_f32_16x16x32_bf16(
                        afh[mt][kk], bvh[nt][kk], acc[mt + 4][nt + 2], 0, 0, 0);
        __builtin_amdgcn_s_setprio(0);
        __builtin_amdgcn_s_barrier();

        // ---- P3 ----
        if (t + 2 < 16) STG(gB0, sBb, t + 2);
        __builtin_amdgcn_s_setprio(1);
#pragma unroll
        for (int kk = 0; kk < 2; ++kk)
#pragma unroll
            for (int mt = 0; mt < 4; ++mt)
#pragma unroll
                for (int nt = 0; nt < 2; ++nt)
                    acc[mt][nt + 2] = __builtin_amdgcn_mfma_f32_16x16x32_bf16(
                        afl[mt][kk], bvh[nt][kk], acc[mt][nt + 2], 0, 0, 0);
        __builtin_amdgcn_s_setprio(0);

        if (t < 15) {
#pragma unroll
            for (int nt = 0; nt < 2; ++nt) {
                bvl[nt][0] = bvln[nt][0];
                bvl[nt][1] = bvln[nt][1];
            }
        }
    }
#undef STG

#pragma unroll
    for (int mt = 0; mt < 8; ++mt) {
#pragma unroll
        for (int nt = 0; nt < 4; ++nt) {
            const int col = n0 + wc * 64 + nt * 16 + lr;
#pragma unroll
            for (int i = 0; i < 4; ++i) {
                const int row = m0 + wr * 128 + mt * 16 + lg * 4 + i;
                Cout[(size_t)row * 1024 + col] =
                    acc[mt][nt][i] + bias[col] + resid[(size_t)row * 1024 + col];
            }
        }
    }
}

// =====================================================================
// KV partials + Ksum partials; quadrant-per-wave, 16 n-splits.
// =====================================================================
__global__ __launch_bounds__(256) void kv_kernel(
    const unsigned short* __restrict__ VT, const unsigned short* __restrict__ KT,
    float* __restrict__ KVTp, float* __restrict__ Ksump)
{
    const int bh = blockIdx.x, sp = blockIdx.y;   // 64 x 16
    const int b = bh >> 4, h = bh & 15;
    const int tid = threadIdx.x, lane = tid & 63, w = tid >> 6;
    const int lr = lane & 15, lg = lane >> 4;
    const int eh = (w >> 1) * 32, dh = (w & 1) * 32;

    f32x4 acc[2][2];
#pragma unroll
    for (int i = 0; i < 2; ++i)
#pragma unroll
        for (int j = 0; j < 2; ++j)
#pragma unroll
            for (int e = 0; e < 4; ++e) acc[i][j][e] = 0.0f;
    float kp[2] = {0.0f, 0.0f};

    const size_t colbase = (size_t)b * 4096 + sp * 256 + lg * 8;
    const unsigned short* va = VT + (size_t)(h * 64 + eh + lr) * NROW + colbase;
    const unsigned short* ka = KT + (size_t)(h * 64 + dh + lr) * NROW + colbase;

    for (int ks = 0; ks < 8; ++ks) {
        short8 af[2], bfv[2];
        af[0]  = *(const short8*)(va + ks * 32);
        af[1]  = *(const short8*)(va + (size_t)16 * NROW + ks * 32);
        bfv[0] = *(const short8*)(ka + ks * 32);
        bfv[1] = *(const short8*)(ka + (size_t)16 * NROW + ks * 32);
#pragma unroll
        for (int mt = 0; mt < 2; ++mt)
#pragma unroll
            for (int nt = 0; nt < 2; ++nt)
                acc[mt][nt] = __builtin_amdgcn_mfma_f32_16x16x32_bf16(
                    af[mt], bfv[nt], acc[mt][nt], 0, 0, 0);
        if (w < 2) {
#pragma unroll
            for (int nt = 0; nt < 2; ++nt)
#pragma unroll
                for (int j = 0; j < 8; ++j)
                    kp[nt] += bf2f((unsigned short)bfv[nt][j]);
        }
    }

    float* out = KVTp + ((size_t)sp * 64 + bh) * 4096;
#pragma unroll
    for (int mt = 0; mt < 2; ++mt)
#pragma unroll
        for (int nt = 0; nt < 2; ++nt)
#pragma unroll
            for (int i = 0; i < 4; ++i)
                out[(eh + mt * 16 + lg * 4 + i) * 64 + dh + nt * 16 + lr] =
                    acc[mt][nt][i];

    if (w < 2) {
#pragma unroll
        for (int nt = 0; nt < 2; ++nt) {
            kp[nt] += __shfl_xor(kp[nt], 16);
            kp[nt] += __shfl_xor(kp[nt], 32);
        }
        if (lane < 16) {
#pragma unroll
            for (int nt = 0; nt < 2; ++nt)
                Ksump[((size_t)sp * 64 + bh) * 64 + dh + nt * 16 + lane] = kp[nt];
        }
    }
}

// =====================================================================
// Reduce the 16 split-partials once: KVs[bh][4096], Ks[bh][64].
// =====================================================================
__global__ __launch_bounds__(256) void kvred_kernel(
    const float* __restrict__ KVTp, const float* __restrict__ Ksump,
    float* __restrict__ KVs, float* __restrict__ Ks)
{
    const int bh = blockIdx.x;
    const int tid = threadIdx.x;
    for (int i = tid * 4; i < 4096; i += 1024) {
        f32x4 s = {0.0f, 0.0f, 0.0f, 0.0f};
#pragma unroll
        for (int sp = 0; sp < 16; ++sp) {
            f32x4 v = *(const f32x4*)(KVTp + ((size_t)sp * 64 + bh) * 4096 + i);
            s[0] += v[0]; s[1] += v[1]; s[2] += v[2]; s[3] += v[3];
        }
        *(f32x4*)(KVs + (size_t)bh * 4096 + i) = s;
    }
    if (tid < 64) {
        float s = 0.0f;
#pragma unroll
        for (int sp = 0; sp < 16; ++sp)
            s += Ksump[((size_t)sp * 64 + bh) * 64 + tid];
        Ks[bh * 64 + tid] = s;
    }
}

// =====================================================================
// A2[n][h*64+e] = (sum_d Q[n][h*64+d] * KV[d][e]) * invZ(n,h); z fused.
// =====================================================================
__global__ __launch_bounds__(256) void a2_kernel(
    const unsigned short* __restrict__ Q, const float* __restrict__ KVs,
    const float* __restrict__ Ks, unsigned short* __restrict__ A2)
{
    const int m0 = blockIdx.x * 128, h = blockIdx.y;
    const int b = m0 >> 12, bh = (b << 4) + h;
    const int tid = threadIdx.x, lane = tid & 63, w = tid >> 6;
    const int wr = w >> 1, wc = w & 1;
    const int lr = lane & 15, lg = lane >> 4;

    __shared__ float ksum_s[64];
    if (tid < 64) ksum_s[tid] = Ks[bh * 64 + tid];
    __syncthreads();

    f32x4 acc[4][2];
#pragma unroll
    for (int i = 0; i < 4; ++i)
#pragma unroll
        for (int j = 0; j < 2; ++j)
#pragma unroll
            for (int e = 0; e < 4; ++e) acc[i][j][e] = 0.0f;
    float zp[4] = {0.0f, 0.0f, 0.0f, 0.0f};

    const unsigned short* qa = Q + (size_t)(m0 + wr * 64 + lr) * DDIM + h * 64 + lg * 8;
    const float* kvb = KVs + (size_t)bh * 4096 + (wc * 32 + lr) * 64 + lg * 8;

#pragma unroll
    for (int ks = 0; ks < 2; ++ks) {
        short8 af[4];
#pragma unroll
        for (int mt = 0; mt < 4; ++mt)
            af[mt] = *(const short8*)(qa + (size_t)mt * 16 * DDIM + ks * 32);
#pragma unroll
        for (int mt = 0; mt < 4; ++mt)
#pragma unroll
            for (int j = 0; j < 8; ++j)
                zp[mt] += bf2f((unsigned short)af[mt][j]) * ksum_s[ks * 32 + lg * 8 + j];
        short8 bfv[2];
#pragma unroll
        for (int nt = 0; nt < 2; ++nt) {
            const float* p = kvb + nt * 16 * 64 + ks * 32;
            f32x4 v0 = *(const f32x4*)(p);
            f32x4 v1 = *(const f32x4*)(p + 4);
            short8 t;
#pragma unroll
            for (int j = 0; j < 4; ++j) {
                t[j]     = (short)f2bf(v0[j]);
                t[j + 4] = (short)f2bf(v1[j]);
            }
            bfv[nt] = t;
        }
#pragma unroll
        for (int mt = 0; mt < 4; ++mt)
#pragma unroll
            for (int nt = 0; nt < 2; ++nt)
                acc[mt][nt] = __builtin_amdgcn_mfma_f32_16x16x32_bf16(
                    af[mt], bfv[nt], acc[mt][nt], 0, 0, 0);
    }

    float zinv[4];
#pragma unroll
    for (int mt = 0; mt < 4; ++mt) {
        zp[mt] += __shfl_xor(zp[mt], 16);
        zp[mt] += __shfl_xor(zp[mt], 32);
        zinv[mt] = 1.0f / fmaxf(zp[mt], 1e-6f);
    }

#pragma unroll
    for (int mt = 0; mt < 4; ++mt)
#pragma unroll
        for (int nt = 0; nt < 2; ++nt)
#pragma unroll
            for (int i = 0; i < 4; ++i) {
                const int row = m0 + wr * 64 + mt * 16 + lg * 4 + i;
                const int col = h * 64 + wc * 32 + nt * 16 + lr;
                const float zi = __shfl(zinv[mt], lg * 4 + i);
                const float v = acc[mt][nt][i] * zi;
                A2[(size_t)row * DDIM + col] = f2bf(v);
            }
}

// =====================================================================
// host
// =====================================================================
extern "C" void kernel_launch(void* const* d_in, const int* in_sizes, int n_in,
                              void* d_out, int out_size, void* d_ws, size_t ws_size,
                              hipStream_t stream)
{
    const float* query   = (const float*)d_in[0];
    const float* context = (const float*)d_in[1];
    const float* q_w = (const float*)d_in[2];
    const float* q_b = (const float*)d_in[3];
    const float* k_w = (const float*)d_in[4];
    const float* k_b = (const float*)d_in[5];
    const float* v_w = (const float*)d_in[6];
    const float* v_b = (const float*)d_in[7];
    const float* o_w = (const float*)d_in[8];
    const float* o_b = (const float*)d_in[9];
    const float* lnq_g = (const float*)d_in[10];
    const float* lnq_b = (const float*)d_in[11];
    const float* lnk_g = (const float*)d_in[12];
    const float* lnk_b = (const float*)d_in[13];

    char* ws = (char*)d_ws;
    unsigned short* WQ  = (unsigned short*)(ws);                    // 0..2 MiB
    unsigned short* WKV = (unsigned short*)(ws + (2u << 20));       // 2..6
    unsigned short* WO  = (unsigned short*)(ws + (6u << 20));       // 6..8
    unsigned short* QLN = (unsigned short*)(ws + (8u << 20));       // 8..40
    unsigned short* CLN = (unsigned short*)(ws + (40u << 20));      // 40..72 (dead after qkv)
    unsigned short* Qm  = (unsigned short*)(ws + (72u << 20));      // 72..104
    unsigned short* KT  = (unsigned short*)(ws + (104u << 20));     // KVT rows 0-1023
    unsigned short* VT  = (unsigned short*)(ws + (136u << 20));     // KVT rows 1024-2047
    float* KVTp  = (float*)(ws + (40u << 20));                      // 16 MiB (16 splits)
    float* Ksump = (float*)(ws + (56u << 20));                      // 256 KiB
    float* KVs   = (float*)(ws + (57u << 20));                      // 1 MiB
    float* Ks    = (float*)(ws + (58u << 20));                      // 16 KiB
    unsigned short* A2 = QLN;                                       // alias (QLN dead)

    ln_kernel<<<8192 + 4096, 256, 0, stream>>>(
        query, context, lnq_g, lnq_b, lnk_g, lnk_b, QLN, CLN,
        q_w, k_w, v_w, o_w, WQ);
    gemm_qkv<<<3072, 256, 0, stream>>>(QLN, WQ, CLN, WKV, Qm, KT,
                                       q_b, k_b, v_b);
    kv_kernel<<<dim3(64, 16), 256, 0, stream>>>(VT, KT, KVTp, Ksump);
    kvred_kernel<<<64, 256, 0, stream>>>(KVTp, Ksump, KVs, Ks);
    a2_kernel<<<dim3(128, 16), 256, 0, stream>>>(Qm, KVs, Ks, A2);
    gemm_out256<<<256, 512, 0, stream>>>(A2, WO, (float*)d_out, o_b, query);
}